// Round 11
// baseline (145.625 us; speedup 1.0000x reference)
//
#include <hip/hip_runtime.h>
#include <cmath>

// SemanticDepthRasterizer — 4-kernel pipeline.
// K1 preprocess: projection/conic (+inv(cam2ego) in double), cull extents.
// K2 rankpack:   O(N^2) rank-by-counting (stable argsort-by-z) + visible pack
//                into 3 float4 SoA param arrays + psem.
// K3 raster_partial: (tile, depth-half) per block -> 1024 blocks x 512 thr
//                (4/CU with refill -> balance + latency hiding), 8 segments
//                per block, exact conic-min-over-rect cull, readlane
//                broadcast, two-pass intra-block combine -> 19-row partials.
//                NOTE: inactive tail lanes MUST be rejected via `inr` in the
//                ballot (R10 bug: clamped duplicate of the last gaussian can
//                pass the AABB test when its center lies inside the tile).
// K4 combine:    (T,C) monoid merge of the two depth halves -> output.

#define MAXC   16     // semantic channels (C==16 here)
#define MAXBM  8
#define NSEGL  8      // segments per block (local)
#define NHALF  2      // depth halves (blocks per tile)
#define RTPB   (NSEGL * 64)   // 512 threads
#define ROWS1  9      // pass-1 rows: T,D,A,S0..S5
#define ROWS2  10     // pass-2 rows: S6..S15
#define PROWS  19     // partial rows: T,D,A,S0..15
#define INVIS_KEY 0x7FFFFFFF

__device__ __forceinline__ float rlf(float x, int l) {
    return __int_as_float(__builtin_amdgcn_readlane(__float_as_int(x), l));
}

// ---- 4x4 inverse (double, adjugate), top-3-rows result ----
__device__ void inv4x4_rows3(const float* __restrict__ src, float* __restrict__ Eout) {
    double m[16];
#pragma unroll
    for (int j = 0; j < 16; ++j) m[j] = (double)src[j];
    double inv[16];
    inv[0]  =  m[5]*m[10]*m[15] - m[5]*m[11]*m[14] - m[9]*m[6]*m[15] + m[9]*m[7]*m[14] + m[13]*m[6]*m[11] - m[13]*m[7]*m[10];
    inv[4]  = -m[4]*m[10]*m[15] + m[4]*m[11]*m[14] + m[8]*m[6]*m[15] - m[8]*m[7]*m[14] - m[12]*m[6]*m[11] + m[12]*m[7]*m[10];
    inv[8]  =  m[4]*m[9]*m[15]  - m[4]*m[11]*m[13] - m[8]*m[5]*m[15] + m[8]*m[7]*m[13] + m[12]*m[5]*m[11] - m[12]*m[7]*m[9];
    inv[12] = -m[4]*m[9]*m[14]  + m[4]*m[10]*m[13] + m[8]*m[5]*m[14] - m[8]*m[6]*m[13] - m[12]*m[5]*m[10] + m[12]*m[6]*m[9];
    inv[1]  = -m[1]*m[10]*m[15] + m[1]*m[11]*m[14] + m[9]*m[2]*m[15] - m[9]*m[3]*m[14] - m[13]*m[2]*m[11] + m[13]*m[3]*m[10];
    inv[5]  =  m[0]*m[10]*m[15] - m[0]*m[11]*m[14] - m[8]*m[2]*m[15] + m[8]*m[3]*m[14] + m[12]*m[2]*m[11] - m[12]*m[3]*m[10];
    inv[9]  = -m[0]*m[9]*m[15]  + m[0]*m[11]*m[13] + m[8]*m[1]*m[15] - m[8]*m[3]*m[13] - m[12]*m[1]*m[11] + m[12]*m[3]*m[9];
    inv[13] =  m[0]*m[9]*m[14]  - m[0]*m[10]*m[13] - m[8]*m[1]*m[14] + m[8]*m[2]*m[13] + m[12]*m[1]*m[10] - m[12]*m[2]*m[9];
    inv[2]  =  m[1]*m[6]*m[15]  - m[1]*m[7]*m[14]  - m[5]*m[2]*m[15] + m[5]*m[3]*m[14] + m[13]*m[2]*m[7]  - m[13]*m[3]*m[6];
    inv[6]  = -m[0]*m[6]*m[15]  + m[0]*m[7]*m[14]  + m[4]*m[2]*m[15] - m[4]*m[3]*m[14] - m[12]*m[2]*m[7]  + m[12]*m[3]*m[6];
    inv[10] =  m[0]*m[5]*m[15]  - m[0]*m[7]*m[13]  - m[4]*m[1]*m[15] + m[4]*m[3]*m[13] + m[12]*m[1]*m[7]  - m[12]*m[3]*m[5];
    inv[14] = -m[0]*m[5]*m[14]  + m[0]*m[6]*m[13]  + m[4]*m[1]*m[14] - m[4]*m[2]*m[13] - m[12]*m[1]*m[6]  + m[12]*m[2]*m[5];
    inv[3]  = -m[1]*m[6]*m[11]  + m[1]*m[7]*m[10]  + m[5]*m[2]*m[11] - m[5]*m[3]*m[10] - m[9]*m[2]*m[7]   + m[9]*m[3]*m[6];
    inv[7]  =  m[0]*m[6]*m[11]  - m[0]*m[7]*m[10]  - m[4]*m[2]*m[11] + m[4]*m[3]*m[10] + m[8]*m[2]*m[7]   - m[8]*m[3]*m[6];
    inv[11] = -m[0]*m[5]*m[11]  + m[0]*m[7]*m[9]   + m[4]*m[1]*m[11] - m[4]*m[3]*m[9]  - m[8]*m[1]*m[7]   + m[8]*m[3]*m[5];
    inv[15] =  m[0]*m[5]*m[10]  - m[0]*m[6]*m[9]   - m[4]*m[1]*m[10] + m[4]*m[2]*m[9]  + m[8]*m[1]*m[6]   - m[8]*m[2]*m[5];
    double det = m[0]*inv[0] + m[1]*inv[4] + m[2]*inv[8] + m[3]*inv[12];
    double rdet = 1.0 / det;
#pragma unroll
    for (int r = 0; r < 3; ++r)
#pragma unroll
        for (int c = 0; c < 4; ++c)
            Eout[r * 4 + c] = (float)(inv[r * 4 + c] * rdet);
}

// ---------------- K1: per-gaussian projection + conic ----------------
__global__ __launch_bounds__(256) void preprocess_kernel(
    const float* __restrict__ means, const float* __restrict__ scales,
    const float* __restrict__ rots,  const float* __restrict__ intr,
    const float* __restrict__ cam2ego,
    int* __restrict__ ikey, float* __restrict__ uu, float* __restrict__ vv,
    float* __restrict__ cia, float* __restrict__ cib, float* __restrict__ cic,
    float* __restrict__ cex, float* __restrict__ cey,
    float* __restrict__ crbc, float* __restrict__ crba,
    int B, int M, int N, int W, int H)
{
    __shared__ float Esh[MAXBM * 12];
    int BM = B * M;
    if (threadIdx.x < (unsigned)BM)
        inv4x4_rows3(cam2ego + (size_t)threadIdx.x * 16, Esh + threadIdx.x * 12);
    __syncthreads();

    int gid = blockIdx.x * 256 + threadIdx.x;
    if (gid >= BM * N) return;
    int bm = gid / N;
    int n  = gid - bm * N;
    int b  = bm / M;
    const float* Ep = Esh + bm * 12;
    const float* mp = means + ((size_t)b * N + n) * 3;
    float mx = mp[0], my = mp[1], mz = mp[2];
    float x_c = Ep[0]*mx + Ep[1]*my + Ep[2]*mz  + Ep[3];
    float y_c = Ep[4]*mx + Ep[5]*my + Ep[6]*mz  + Ep[7];
    float z   = Ep[8]*mx + Ep[9]*my + Ep[10]*mz + Ep[11];
    const float* K = intr + (size_t)bm * 16;
    float fx = K[0], fy = K[5], cx = K[2], cy = K[6];
    float zs = fmaxf(z, 1e-4f);
    float u = x_c / zs * fx + cx;
    float v = y_c / zs * fy + cy;
    const float* qp = rots + ((size_t)b * N + n) * 4;
    float qw = qp[0], qx = qp[1], qy = qp[2], qz = qp[3];
    float qn = sqrtf(qw*qw + qx*qx + qy*qy + qz*qz);
    qw /= qn; qx /= qn; qy /= qn; qz /= qn;
    float R00 = 1.f - 2.f*(qy*qy + qz*qz), R01 = 2.f*(qx*qy - qz*qw), R02 = 2.f*(qx*qz + qy*qw);
    float R10 = 2.f*(qx*qy + qz*qw), R11 = 1.f - 2.f*(qx*qx + qz*qz), R12 = 2.f*(qy*qz - qx*qw);
    float R20 = 2.f*(qx*qz - qy*qw), R21 = 2.f*(qy*qz + qx*qw), R22 = 1.f - 2.f*(qx*qx + qy*qy);
    const float* sp = scales + ((size_t)b * N + n) * 3;
    float s0 = sp[0]*sp[0], s1 = sp[1]*sp[1], s2 = sp[2]*sp[2];
    float S00 = R00*R00*s0 + R01*R01*s1 + R02*R02*s2;
    float S01 = R00*R10*s0 + R01*R11*s1 + R02*R12*s2;
    float S02 = R00*R20*s0 + R01*R21*s1 + R02*R22*s2;
    float S11 = R10*R10*s0 + R11*R11*s1 + R12*R12*s2;
    float S12 = R10*R20*s0 + R11*R21*s1 + R12*R22*s2;
    float S22 = R20*R20*s0 + R21*R21*s1 + R22*R22*s2;
    float W00 = Ep[0], W01 = Ep[1], W02 = Ep[2];
    float W10 = Ep[4], W11 = Ep[5], W12 = Ep[6];
    float W20 = Ep[8], W21 = Ep[9], W22 = Ep[10];
    float A00 = W00*S00 + W01*S01 + W02*S02;
    float A01 = W00*S01 + W01*S11 + W02*S12;
    float A02 = W00*S02 + W01*S12 + W02*S22;
    float A10 = W10*S00 + W11*S01 + W12*S02;
    float A11 = W10*S01 + W11*S11 + W12*S12;
    float A12 = W10*S02 + W11*S12 + W12*S22;
    float A20 = W20*S00 + W21*S01 + W22*S02;
    float A21 = W20*S01 + W21*S11 + W22*S12;
    float A22 = W20*S02 + W21*S12 + W22*S22;
    float Sc00 = A00*W00 + A01*W01 + A02*W02;
    float Sc01 = A00*W10 + A01*W11 + A02*W12;
    float Sc02 = A00*W20 + A01*W21 + A02*W22;
    float Sc11 = A10*W10 + A11*W11 + A12*W12;
    float Sc12 = A10*W20 + A11*W21 + A12*W22;
    float Sc22 = A20*W20 + A21*W21 + A22*W22;
    float j00 = fx / zs,  j02 = -fx * x_c / (zs * zs);
    float j11 = fy / zs,  j12 = -fy * y_c / (zs * zs);
    float c00 = j00*j00*Sc00 + 2.f*j00*j02*Sc02 + j02*j02*Sc22;
    float c01 = j00*(Sc01*j11 + Sc02*j12) + j02*(Sc12*j11 + Sc22*j12);
    float c11 = j11*j11*Sc11 + 2.f*j11*j12*Sc12 + j12*j12*Sc22;
    float a  = fmaxf(c00, 0.3f);
    float cc = fmaxf(c11, 0.3f);
    float bb = c01;
    float det = a * cc - bb * bb;
    bool valid = (z > 0.01f) && (det > 1e-8f);
    float det_s = (det > 1e-8f) ? det : 1.0f;
    float ia = cc / det_s, ib = -bb / det_s, ic = a / det_s;
    uu[gid] = u;  vv[gid] = v;
    cia[gid] = ia;  cib[gid] = ib;  cic[gid] = ic;
    cex[gid] = sqrtf(34.0f * a);    // ellipse {d2<=34} AABB half-extents
    cey[gid] = sqrtf(34.0f * cc);
    crbc[gid] = -bb / a;            // edge-min ratios (div-free raster)
    crba[gid] = -bb / cc;
    bool visible = valid && (z > 0.1f) &&
                   (u >= 0.f) && (u < (float)W) && (v >= 0.f) && (v < (float)H);
    ikey[gid] = visible ? __float_as_int(z) : INVIS_KEY;
}

// -- K2: rank one 64-i chunk per block (stable argsort by z) + pack --
__global__ __launch_bounds__(64) void rankpack_kernel(
    const int* __restrict__ ikey,
    const float* __restrict__ uu, const float* __restrict__ vv,
    const float* __restrict__ cia, const float* __restrict__ cib,
    const float* __restrict__ cic, const float* __restrict__ cex,
    const float* __restrict__ cey, const float* __restrict__ crbc,
    const float* __restrict__ crba,
    const float* __restrict__ opac, const float* __restrict__ sem,
    float4* __restrict__ pk0, float4* __restrict__ pk1,
    float4* __restrict__ pk2,
    float* __restrict__ psem, int* __restrict__ pcount,
    int B, int M, int N, int C)
{
    int lane  = threadIdx.x & 63;
    int nch64 = (N + 63) >> 6;
    int chunk = blockIdx.x;
    int bm = chunk / nch64;
    int cl = chunk - bm * nch64;
    int i  = (cl << 6) + lane;
    const int* kb = ikey + (size_t)bm * N;
    int ki  = (i < N) ? kb[i] : INVIS_KEY;
    int kip = ki + 1;
    int rank = 0, tot = 0;
    int kj = (lane < N) ? kb[lane] : INVIS_KEY;
    for (int jc = 0; jc < nch64; ++jc) {
        int kcur = kj;
        if (jc + 1 < nch64) {
            int jn = ((jc + 1) << 6) + lane;
            kj = (jn < N) ? kb[jn] : INVIS_KEY;
        }
        tot += (int)__popcll(__ballot(kcur != INVIS_KEY));
        if (jc < cl) {
#pragma unroll
            for (int gg = 0; gg < 64; ++gg)
                rank += (__builtin_amdgcn_readlane(kcur, gg) < kip);
        } else if (jc > cl) {
#pragma unroll
            for (int gg = 0; gg < 64; ++gg)
                rank += (__builtin_amdgcn_readlane(kcur, gg) < ki);
        } else {
#pragma unroll
            for (int gg = 0; gg < 64; ++gg) {
                int kk = (gg < lane) ? kip : ki;
                rank += (__builtin_amdgcn_readlane(kcur, gg) < kk);
            }
        }
    }
    if (cl == 0 && lane == 0) pcount[bm] = tot;
    if (i < N && ki != INVIS_KEY) {
        int b = bm / M;
        size_t src = (size_t)bm * N + i;
        size_t dst = (size_t)bm * N + rank;
        float z = __int_as_float(ki);
        pk0[dst] = make_float4(uu[src], vv[src], cex[src], cey[src]);
        pk1[dst] = make_float4(cia[src], cib[src], cic[src],
                               opac[(size_t)b * N + i]);
        pk2[dst] = make_float4(fminf(fmaxf(z, 0.1f), 100.0f),
                               crbc[src], crba[src], 0.f);
        const float* spc = sem + ((size_t)b * N + i) * C;
        float* dpc = psem + dst * C;
        int c4 = C & ~3;
        for (int q = 0; q < c4; q += 4)
            *(float4*)(dpc + q) = *(const float4*)(spc + q);
        for (int q = c4; q < C; ++q) dpc[q] = spc[q];
    }
}

// ---- K3: one (8x8 tile, depth half) per block, 8 segments x 8 waves ----
__global__ __launch_bounds__(RTPB) void raster_partial_kernel(
    const float4* __restrict__ pk0, const float4* __restrict__ pk1,
    const float4* __restrict__ pk2,
    const float* __restrict__ psem, const int* __restrict__ pcount,
    float* __restrict__ part,
    int BM, int N, int C, int H, int W, int ntx, int nty)
{
    __shared__ float comb[NSEGL * ROWS2 * 64];   // 20 KB
    int wave = threadIdx.x >> 6;
    int lane = threadIdx.x & 63;
    int bh   = blockIdx.x;           // tile*2 + half
    int tile = bh >> 1;
    int half = bh & 1;
    int tpv = ntx * nty;
    int bm  = tile / tpv;
    int rem = tile - bm * tpv;
    int tyi = rem / ntx;
    int txi = rem - tyi * ntx;
    int lx = lane & 7, ly = lane >> 3;
    float fxp = (float)(txi * 8 + lx), fyp = (float)(tyi * 8 + ly);
    float x0 = (float)(txi * 8),     y0 = (float)(tyi * 8);
    float x1 = (float)(txi * 8 + 7), y1 = (float)(tyi * 8 + 7);

    int cnt = pcount[bm];
    int seg = (cnt + NSEGL * NHALF - 1) / (NSEGL * NHALF);
    int wg  = half * NSEGL + wave;   // global segment index 0..15
    int gs = wg * seg;
    int ge = min(gs + seg, cnt);

    float T = 1.0f, accA = 0.f, accD = 0.f;
    float accS[MAXC];
#pragma unroll
    for (int q = 0; q < MAXC; ++q) accS[q] = 0.f;

    for (int base = gs; base < ge; base += 64) {
        if (!__any(T >= 1e-6f)) break;
        int g = base + lane;
        bool inr = g < ge;
        int gc = inr ? g : (ge - 1);       // clamped load; rejected via `inr`
        size_t src = (size_t)bm * N + gc;
        float4 P0 = pk0[src];        // u, v, ex, ey
        float4 P1 = pk1[src];        // ia, ib, ic, op
        float4 P2 = pk2[src];        // dz, rbc, rba, -
        // --- exact conic-min-over-rect cull ---
        float dx0 = x0 - P0.x, dx1 = x1 - P0.x;
        float dy0 = y0 - P0.y, dy1 = y1 - P0.y;
        bool aabb = (dx0 <= P0.z) && (-dx1 <= P0.z) &&
                    (dy0 <= P0.w) && (-dy1 <= P0.w);
        bool inside = (dx0 <= 0.f) && (dx1 >= 0.f) && (dy0 <= 0.f) && (dy1 >= 0.f);
        float t, q0, q1, q2, q3;
        t  = fminf(fmaxf(P2.y * dx0, dy0), dy1);   // rbc ratio
        q0 = P1.x * dx0 * dx0 + t * (P1.z * t + 2.f * P1.y * dx0);
        t  = fminf(fmaxf(P2.y * dx1, dy0), dy1);
        q1 = P1.x * dx1 * dx1 + t * (P1.z * t + 2.f * P1.y * dx1);
        t  = fminf(fmaxf(P2.z * dy0, dx0), dx1);   // rba ratio
        q2 = P1.z * dy0 * dy0 + t * (P1.x * t + 2.f * P1.y * dy0);
        t  = fminf(fmaxf(P2.z * dy1, dx0), dx1);
        q3 = P1.z * dy1 * dy1 + t * (P1.x * t + 2.f * P1.y * dy1);
        float mind2 = inside ? 0.f : fminf(fminf(q0, q1), fminf(q2, q3));
        unsigned long long mask = __ballot(inr && aabb && (mind2 <= 34.0f));
        float sf[MAXC];
        if ((mask >> lane) & 1ull) {
            const float4* spc = (const float4*)(psem + src * MAXC);
#pragma unroll
            for (int q = 0; q < MAXC / 4; ++q) {
                float4 f = spc[q];
                sf[q*4+0] = f.x; sf[q*4+1] = f.y; sf[q*4+2] = f.z; sf[q*4+3] = f.w;
            }
        }
        while (mask) {
            int gg = __ffsll(mask) - 1;   // increasing = front-to-back
            mask &= mask - 1;
            float u  = rlf(P0.x, gg), v  = rlf(P0.y, gg);
            float ia = rlf(P1.x, gg), ib = rlf(P1.y, gg), ic = rlf(P1.z, gg);
            float dx = fxp - u, dy = fyp - v;
            float d2 = ia*dx*dx + ic*dy*dy + 2.0f*ib*(dx*dy);
            float gvl = __expf(-0.5f * d2);
            float alpha = fminf(rlf(P1.w, gg) * gvl, 0.99f);
            float w = T * alpha;
            T -= w;
            accD += w * rlf(P2.x, gg);
            accA += w;
#pragma unroll
            for (int ch = 0; ch < MAXC; ++ch) accS[ch] += w * rlf(sf[ch], gg);
        }
    }

    // ---- two-pass combine of 8 local segments -> 19-row partial ----
    float* pout = part + (size_t)bh * (PROWS * 64);
    // pass 1 rows: 0=T, 1=D, 2=A, 3..8=S0..S5
    float* my = comb + (wave * ROWS1) * 64 + lane;
    my[0 * 64] = T;
    my[1 * 64] = accD;
    my[2 * 64] = accA;
#pragma unroll
    for (int k = 0; k < 6; ++k) my[(3 + k) * 64] = accS[k];
    __syncthreads();

    int px = lane;
    float pre[NSEGL];
    pre[0] = 1.f;
#pragma unroll
    for (int w = 1; w < NSEGL; ++w)
        pre[w] = pre[w-1] * comb[((w-1) * ROWS1) * 64 + px];

    for (int o = wave; o < 9; o += NSEGL) {
        float val;
        if (o == 0) {
            val = pre[NSEGL-1] * comb[((NSEGL-1) * ROWS1) * 64 + px]; // T_total
        } else {
            val = 0.f;
#pragma unroll
            for (int w = 0; w < NSEGL; ++w)
                val += pre[w] * comb[(w * ROWS1 + o) * 64 + px];
        }
        pout[o * 64 + px] = val;
    }
    __syncthreads();

    // pass 2 rows: 0..9 = S6..S15 -> partial rows 9..18
    float* my2 = comb + (wave * ROWS2) * 64 + lane;
#pragma unroll
    for (int k = 0; k < 10; ++k) my2[k * 64] = accS[6 + k];
    __syncthreads();

    for (int o = wave; o < 10; o += NSEGL) {
        float val = 0.f;
#pragma unroll
        for (int w = 0; w < NSEGL; ++w)
            val += pre[w] * comb[(w * ROWS2 + o) * 64 + px];
        pout[(9 + o) * 64 + px] = val;
    }
}

// ---- K4: merge depth halves: C = C0 + T0*C1 ; scatter to output ----
__global__ __launch_bounds__(64) void combine_kernel(
    const float* __restrict__ part, float* __restrict__ out,
    int BM, int C, int H, int W, int ntx, int nty)
{
    int tile = blockIdx.x;
    int px   = threadIdx.x;
    int tpv = ntx * nty;
    int bm  = tile / tpv;
    int rem = tile - bm * tpv;
    int tyi = rem / ntx;
    int txi = rem - tyi * ntx;
    int pxx = txi * 8 + (px & 7);
    int pyy = tyi * 8 + (px >> 3);
    if (pxx >= W || pyy >= H) return;
    size_t HW  = (size_t)H * W;
    size_t pix = (size_t)pyy * W + pxx;
    size_t BMHW = (size_t)BM * HW;
    const float* a = part + (size_t)(tile * 2 + 0) * (PROWS * 64);
    const float* b = part + (size_t)(tile * 2 + 1) * (PROWS * 64);
    float T0 = a[0 * 64 + px];
    // row 1 = depth, row 2 = alpha, rows 3..18 = sem 0..15
    out[(size_t)bm * HW + pix] = a[1*64+px] + T0 * b[1*64+px];
    out[BMHW + BMHW * C + (size_t)bm * HW + pix] = a[2*64+px] + T0 * b[2*64+px];
    float* semo = out + BMHW + (size_t)bm * C * HW + pix;
    for (int k = 0; k < C && k < MAXC; ++k)
        semo[(size_t)k * HW] = a[(3+k)*64+px] + T0 * b[(3+k)*64+px];
}

extern "C" void kernel_launch(void* const* d_in, const int* in_sizes, int n_in,
                              void* d_out, int out_size, void* d_ws, size_t ws_size,
                              hipStream_t stream) {
    const float* means  = (const float*)d_in[0];
    const float* scales = (const float*)d_in[1];
    const float* rots   = (const float*)d_in[2];
    const float* opac   = (const float*)d_in[3];
    const float* sem    = (const float*)d_in[4];
    const float* intr   = (const float*)d_in[5];
    const float* c2e    = (const float*)d_in[6];
    float* out = (float*)d_out;

    int B  = 1;
    int BM = in_sizes[6] / 16;         // cam2ego is (B,M,4,4)
    int M  = BM / B;
    int N  = in_sizes[0] / (3 * B);    // means (B,N,3)
    int C  = in_sizes[4] / (B * N);    // semantic_features (B,N,C)
    long HWl = (long)out_size / ((long)BM * (C + 2));
    int H = (int)(sqrt((double)HWl) + 0.5);
    int W = (int)(HWl / H);
    int ntx = (W + 7) / 8, nty = (H + 7) / 8;
    int ntiles = ntx * nty * BM;
    int nch64  = (N + 63) >> 6;

    float* ws = (float*)d_ws;
    size_t off = 0;
    size_t BMN  = (size_t)BM * N;
    int*   ikey = (int*)(ws + off); off += BMN;
    float* uu   = ws + off; off += BMN;
    float* vv   = ws + off; off += BMN;
    float* cia  = ws + off; off += BMN;
    float* cib  = ws + off; off += BMN;
    float* cic  = ws + off; off += BMN;
    float* cex  = ws + off; off += BMN;
    float* cey  = ws + off; off += BMN;
    float* crbc = ws + off; off += BMN;
    float* crba = ws + off; off += BMN;
    off = (off + 3) & ~(size_t)3;            // float4 alignment
    float4* pk0 = (float4*)(ws + off); off += BMN * 4;
    float4* pk1 = (float4*)(ws + off); off += BMN * 4;
    float4* pk2 = (float4*)(ws + off); off += BMN * 4;
    float* psem = ws + off; off += BMN * C;
    int* pcount = (int*)(ws + off); off += BM + 3;
    float* part = ws + off; off += (size_t)ntiles * 2 * PROWS * 64;

    int tot = BM * N;
    preprocess_kernel<<<(tot + 255) / 256, 256, 0, stream>>>(
        means, scales, rots, intr, c2e,
        ikey, uu, vv, cia, cib, cic, cex, cey, crbc, crba, B, M, N, W, H);

    rankpack_kernel<<<BM * nch64, 64, 0, stream>>>(
        ikey, uu, vv, cia, cib, cic, cex, cey, crbc, crba, opac, sem,
        pk0, pk1, pk2, psem, pcount, B, M, N, C);

    raster_partial_kernel<<<ntiles * 2, RTPB, 0, stream>>>(
        pk0, pk1, pk2, psem, pcount, part, BM, N, C, H, W, ntx, nty);

    combine_kernel<<<ntiles, 64, 0, stream>>>(
        part, out, BM, C, H, W, ntx, nty);
}

// Round 12
// 139.452 us; speedup vs baseline: 1.0443x; 1.0443x over previous
//
#include <hip/hip_runtime.h>
#include <cmath>

// SemanticDepthRasterizer — 3-kernel pipeline (R9 structure + scalar-broadcast
// survivor loop).
// K1 preprocess: projection/conic (+inv(cam2ego) in double), cull extents.
// K2 rankpack:   O(N^2) rank-by-counting (stable argsort-by-z) + visible pack
//                into 3 float4 SoA param arrays + psem.
// K3 raster:     one 8x8 tile per block, NSEG=16 depth segments x 16 waves,
//                exact conic-min-over-rect cull, then survivor processing via
//                WAVE-UNIFORM SCALAR LOADS (s_load through readfirstlane'd
//                index, software-pipelined depth 1) instead of v_readlane
//                broadcast — removes the VALU->SGPR hazard chain that R8-R11
//                counters implicate (VALUBusy*dur const ~14us, dur stuck 42-50),
//                two-pass prefix-transmittance combine.

#define MAXC   16     // semantic channels (C==16 here)
#define MAXBM  8
#define NSEG   16     // depth segments == waves per raster block
#define RTPB   (NSEG * 64)   // 1024 threads
#define ROWS1  9      // pass-1 rows: T,D,A,S0..S5
#define ROWS2  10     // pass-2 rows: S6..S15
#define INVIS_KEY 0x7FFFFFFF

// ---- 4x4 inverse (double, adjugate), top-3-rows result ----
__device__ void inv4x4_rows3(const float* __restrict__ src, float* __restrict__ Eout) {
    double m[16];
#pragma unroll
    for (int j = 0; j < 16; ++j) m[j] = (double)src[j];
    double inv[16];
    inv[0]  =  m[5]*m[10]*m[15] - m[5]*m[11]*m[14] - m[9]*m[6]*m[15] + m[9]*m[7]*m[14] + m[13]*m[6]*m[11] - m[13]*m[7]*m[10];
    inv[4]  = -m[4]*m[10]*m[15] + m[4]*m[11]*m[14] + m[8]*m[6]*m[15] - m[8]*m[7]*m[14] - m[12]*m[6]*m[11] + m[12]*m[7]*m[10];
    inv[8]  =  m[4]*m[9]*m[15]  - m[4]*m[11]*m[13] - m[8]*m[5]*m[15] + m[8]*m[7]*m[13] + m[12]*m[5]*m[11] - m[12]*m[7]*m[9];
    inv[12] = -m[4]*m[9]*m[14]  + m[4]*m[10]*m[13] + m[8]*m[5]*m[14] - m[8]*m[6]*m[13] - m[12]*m[5]*m[10] + m[12]*m[6]*m[9];
    inv[1]  = -m[1]*m[10]*m[15] + m[1]*m[11]*m[14] + m[9]*m[2]*m[15] - m[9]*m[3]*m[14] - m[13]*m[2]*m[11] + m[13]*m[3]*m[10];
    inv[5]  =  m[0]*m[10]*m[15] - m[0]*m[11]*m[14] - m[8]*m[2]*m[15] + m[8]*m[3]*m[14] + m[12]*m[2]*m[11] - m[12]*m[3]*m[10];
    inv[9]  = -m[0]*m[9]*m[15]  + m[0]*m[11]*m[13] + m[8]*m[1]*m[15] - m[8]*m[3]*m[13] - m[12]*m[1]*m[11] + m[12]*m[3]*m[9];
    inv[13] =  m[0]*m[9]*m[14]  - m[0]*m[10]*m[13] - m[8]*m[1]*m[14] + m[8]*m[2]*m[13] + m[12]*m[1]*m[10] - m[12]*m[2]*m[9];
    inv[2]  =  m[1]*m[6]*m[15]  - m[1]*m[7]*m[14]  - m[5]*m[2]*m[15] + m[5]*m[3]*m[14] + m[13]*m[2]*m[7]  - m[13]*m[3]*m[6];
    inv[6]  = -m[0]*m[6]*m[15]  + m[0]*m[7]*m[14]  + m[4]*m[2]*m[15] - m[4]*m[3]*m[14] - m[12]*m[2]*m[7]  + m[12]*m[3]*m[6];
    inv[10] =  m[0]*m[5]*m[15]  - m[0]*m[7]*m[13]  - m[4]*m[1]*m[15] + m[4]*m[3]*m[13] + m[12]*m[1]*m[7]  - m[12]*m[3]*m[5];
    inv[14] = -m[0]*m[5]*m[14]  + m[0]*m[6]*m[13]  + m[4]*m[1]*m[14] - m[4]*m[2]*m[13] - m[12]*m[1]*m[6]  + m[12]*m[2]*m[5];
    inv[3]  = -m[1]*m[6]*m[11]  + m[1]*m[7]*m[10]  + m[5]*m[2]*m[11] - m[5]*m[3]*m[10] - m[9]*m[2]*m[7]   + m[9]*m[3]*m[6];
    inv[7]  =  m[0]*m[6]*m[11]  - m[0]*m[7]*m[10]  - m[4]*m[2]*m[11] + m[4]*m[3]*m[10] + m[8]*m[2]*m[7]   - m[8]*m[3]*m[6];
    inv[11] = -m[0]*m[5]*m[11]  + m[0]*m[7]*m[9]   + m[4]*m[1]*m[11] - m[4]*m[3]*m[9]  - m[8]*m[1]*m[7]   + m[8]*m[3]*m[5];
    inv[15] =  m[0]*m[5]*m[10]  - m[0]*m[6]*m[9]   - m[4]*m[1]*m[10] + m[4]*m[2]*m[9]  + m[8]*m[1]*m[6]   - m[8]*m[2]*m[5];
    double det = m[0]*inv[0] + m[1]*inv[4] + m[2]*inv[8] + m[3]*inv[12];
    double rdet = 1.0 / det;
#pragma unroll
    for (int r = 0; r < 3; ++r)
#pragma unroll
        for (int c = 0; c < 4; ++c)
            Eout[r * 4 + c] = (float)(inv[r * 4 + c] * rdet);
}

// ---------------- K1: per-gaussian projection + conic ----------------
__global__ __launch_bounds__(256) void preprocess_kernel(
    const float* __restrict__ means, const float* __restrict__ scales,
    const float* __restrict__ rots,  const float* __restrict__ intr,
    const float* __restrict__ cam2ego,
    int* __restrict__ ikey, float* __restrict__ uu, float* __restrict__ vv,
    float* __restrict__ cia, float* __restrict__ cib, float* __restrict__ cic,
    float* __restrict__ cex, float* __restrict__ cey,
    float* __restrict__ crbc, float* __restrict__ crba,
    int B, int M, int N, int W, int H)
{
    __shared__ float Esh[MAXBM * 12];
    int BM = B * M;
    if (threadIdx.x < (unsigned)BM)
        inv4x4_rows3(cam2ego + (size_t)threadIdx.x * 16, Esh + threadIdx.x * 12);
    __syncthreads();

    int gid = blockIdx.x * 256 + threadIdx.x;
    if (gid >= BM * N) return;
    int bm = gid / N;
    int n  = gid - bm * N;
    int b  = bm / M;
    const float* Ep = Esh + bm * 12;
    const float* mp = means + ((size_t)b * N + n) * 3;
    float mx = mp[0], my = mp[1], mz = mp[2];
    float x_c = Ep[0]*mx + Ep[1]*my + Ep[2]*mz  + Ep[3];
    float y_c = Ep[4]*mx + Ep[5]*my + Ep[6]*mz  + Ep[7];
    float z   = Ep[8]*mx + Ep[9]*my + Ep[10]*mz + Ep[11];
    const float* K = intr + (size_t)bm * 16;
    float fx = K[0], fy = K[5], cx = K[2], cy = K[6];
    float zs = fmaxf(z, 1e-4f);
    float u = x_c / zs * fx + cx;
    float v = y_c / zs * fy + cy;
    const float* qp = rots + ((size_t)b * N + n) * 4;
    float qw = qp[0], qx = qp[1], qy = qp[2], qz = qp[3];
    float qn = sqrtf(qw*qw + qx*qx + qy*qy + qz*qz);
    qw /= qn; qx /= qn; qy /= qn; qz /= qn;
    float R00 = 1.f - 2.f*(qy*qy + qz*qz), R01 = 2.f*(qx*qy - qz*qw), R02 = 2.f*(qx*qz + qy*qw);
    float R10 = 2.f*(qx*qy + qz*qw), R11 = 1.f - 2.f*(qx*qx + qz*qz), R12 = 2.f*(qy*qz - qx*qw);
    float R20 = 2.f*(qx*qz - qy*qw), R21 = 2.f*(qy*qz + qx*qw), R22 = 1.f - 2.f*(qx*qx + qy*qy);
    const float* sp = scales + ((size_t)b * N + n) * 3;
    float s0 = sp[0]*sp[0], s1 = sp[1]*sp[1], s2 = sp[2]*sp[2];
    float S00 = R00*R00*s0 + R01*R01*s1 + R02*R02*s2;
    float S01 = R00*R10*s0 + R01*R11*s1 + R02*R12*s2;
    float S02 = R00*R20*s0 + R01*R21*s1 + R02*R22*s2;
    float S11 = R10*R10*s0 + R11*R11*s1 + R12*R12*s2;
    float S12 = R10*R20*s0 + R11*R21*s1 + R12*R22*s2;
    float S22 = R20*R20*s0 + R21*R21*s1 + R22*R22*s2;
    float W00 = Ep[0], W01 = Ep[1], W02 = Ep[2];
    float W10 = Ep[4], W11 = Ep[5], W12 = Ep[6];
    float W20 = Ep[8], W21 = Ep[9], W22 = Ep[10];
    float A00 = W00*S00 + W01*S01 + W02*S02;
    float A01 = W00*S01 + W01*S11 + W02*S12;
    float A02 = W00*S02 + W01*S12 + W02*S22;
    float A10 = W10*S00 + W11*S01 + W12*S02;
    float A11 = W10*S01 + W11*S11 + W12*S12;
    float A12 = W10*S02 + W11*S12 + W12*S22;
    float A20 = W20*S00 + W21*S01 + W22*S02;
    float A21 = W20*S01 + W21*S11 + W22*S12;
    float A22 = W20*S02 + W21*S12 + W22*S22;
    float Sc00 = A00*W00 + A01*W01 + A02*W02;
    float Sc01 = A00*W10 + A01*W11 + A02*W12;
    float Sc02 = A00*W20 + A01*W21 + A02*W22;
    float Sc11 = A10*W10 + A11*W11 + A12*W12;
    float Sc12 = A10*W20 + A11*W21 + A12*W22;
    float Sc22 = A20*W20 + A21*W21 + A22*W22;
    float j00 = fx / zs,  j02 = -fx * x_c / (zs * zs);
    float j11 = fy / zs,  j12 = -fy * y_c / (zs * zs);
    float c00 = j00*j00*Sc00 + 2.f*j00*j02*Sc02 + j02*j02*Sc22;
    float c01 = j00*(Sc01*j11 + Sc02*j12) + j02*(Sc12*j11 + Sc22*j12);
    float c11 = j11*j11*Sc11 + 2.f*j11*j12*Sc12 + j12*j12*Sc22;
    float a  = fmaxf(c00, 0.3f);
    float cc = fmaxf(c11, 0.3f);
    float bb = c01;
    float det = a * cc - bb * bb;
    bool valid = (z > 0.01f) && (det > 1e-8f);
    float det_s = (det > 1e-8f) ? det : 1.0f;
    float ia = cc / det_s, ib = -bb / det_s, ic = a / det_s;
    uu[gid] = u;  vv[gid] = v;
    cia[gid] = ia;  cib[gid] = ib;  cic[gid] = ic;
    cex[gid] = sqrtf(34.0f * a);    // ellipse {d2<=34} AABB half-extents
    cey[gid] = sqrtf(34.0f * cc);
    crbc[gid] = -bb / a;            // edge-min ratios (div-free raster)
    crba[gid] = -bb / cc;
    bool visible = valid && (z > 0.1f) &&
                   (u >= 0.f) && (u < (float)W) && (v >= 0.f) && (v < (float)H);
    ikey[gid] = visible ? __float_as_int(z) : INVIS_KEY;
}

// -- K2: rank one 64-i chunk per block (stable argsort by z) + pack --
__global__ __launch_bounds__(64) void rankpack_kernel(
    const int* __restrict__ ikey,
    const float* __restrict__ uu, const float* __restrict__ vv,
    const float* __restrict__ cia, const float* __restrict__ cib,
    const float* __restrict__ cic, const float* __restrict__ cex,
    const float* __restrict__ cey, const float* __restrict__ crbc,
    const float* __restrict__ crba,
    const float* __restrict__ opac, const float* __restrict__ sem,
    float4* __restrict__ pk0, float4* __restrict__ pk1,
    float4* __restrict__ pk2,
    float* __restrict__ psem, int* __restrict__ pcount,
    int B, int M, int N, int C)
{
    int lane  = threadIdx.x & 63;
    int nch64 = (N + 63) >> 6;
    int chunk = blockIdx.x;
    int bm = chunk / nch64;
    int cl = chunk - bm * nch64;
    int i  = (cl << 6) + lane;
    const int* kb = ikey + (size_t)bm * N;
    int ki  = (i < N) ? kb[i] : INVIS_KEY;
    int kip = ki + 1;
    int rank = 0, tot = 0;
    int kj = (lane < N) ? kb[lane] : INVIS_KEY;
    for (int jc = 0; jc < nch64; ++jc) {
        int kcur = kj;
        if (jc + 1 < nch64) {
            int jn = ((jc + 1) << 6) + lane;
            kj = (jn < N) ? kb[jn] : INVIS_KEY;
        }
        tot += (int)__popcll(__ballot(kcur != INVIS_KEY));
        if (jc < cl) {
#pragma unroll
            for (int gg = 0; gg < 64; ++gg)
                rank += (__builtin_amdgcn_readlane(kcur, gg) < kip);
        } else if (jc > cl) {
#pragma unroll
            for (int gg = 0; gg < 64; ++gg)
                rank += (__builtin_amdgcn_readlane(kcur, gg) < ki);
        } else {
#pragma unroll
            for (int gg = 0; gg < 64; ++gg) {
                int kk = (gg < lane) ? kip : ki;
                rank += (__builtin_amdgcn_readlane(kcur, gg) < kk);
            }
        }
    }
    if (cl == 0 && lane == 0) pcount[bm] = tot;
    if (i < N && ki != INVIS_KEY) {
        int b = bm / M;
        size_t src = (size_t)bm * N + i;
        size_t dst = (size_t)bm * N + rank;
        float z = __int_as_float(ki);
        pk0[dst] = make_float4(uu[src], vv[src], cex[src], cey[src]);
        pk1[dst] = make_float4(cia[src], cib[src], cic[src],
                               opac[(size_t)b * N + i]);
        pk2[dst] = make_float4(fminf(fmaxf(z, 0.1f), 100.0f),
                               crbc[src], crba[src], 0.f);
        const float* spc = sem + ((size_t)b * N + i) * C;
        float* dpc = psem + dst * C;
        int c4 = C & ~3;
        for (int q = 0; q < c4; q += 4)
            *(float4*)(dpc + q) = *(const float4*)(spc + q);
        for (int q = c4; q < C; ++q) dpc[q] = spc[q];
    }
}

// ---- K3: one 8x8 tile per block, 16 depth segments x 16 waves ----
__global__ __launch_bounds__(RTPB) void raster_kernel(
    const float4* __restrict__ pk0, const float4* __restrict__ pk1,
    const float4* __restrict__ pk2,
    const float* __restrict__ psem, const int* __restrict__ pcount,
    float* __restrict__ out,
    int BM, int N, int C, int H, int W, int ntx, int nty)
{
    __shared__ float comb[NSEG * ROWS2 * 64];   // 40 KB; pass1 uses ROWS1 rows
    int wave = threadIdx.x >> 6;
    int lane = threadIdx.x & 63;
    int tile = blockIdx.x;
    int tpv = ntx * nty;
    int bm  = tile / tpv;
    int rem = tile - bm * tpv;
    int tyi = rem / ntx;
    int txi = rem - tyi * ntx;
    int lx = lane & 7, ly = lane >> 3;
    float fxp = (float)(txi * 8 + lx), fyp = (float)(tyi * 8 + ly);
    float x0 = (float)(txi * 8),     y0 = (float)(tyi * 8);
    float x1 = (float)(txi * 8 + 7), y1 = (float)(tyi * 8 + 7);

    int cnt = pcount[bm];
    int seg = (cnt + NSEG - 1) / NSEG;
    int gs = wave * seg;
    int ge = min(gs + seg, cnt);

    float T = 1.0f, accA = 0.f, accD = 0.f;
    float accS[MAXC];
#pragma unroll
    for (int q = 0; q < MAXC; ++q) accS[q] = 0.f;

    for (int base = gs; base < ge; base += 64) {
        if (!__any(T >= 1e-6f)) break;
        int g = base + lane;
        bool inr = g < ge;
        int gc = inr ? g : (ge - 1);       // clamped load; rejected via `inr`
        size_t src = (size_t)bm * N + gc;
        float4 P0 = pk0[src];        // u, v, ex, ey
        float4 P1 = pk1[src];        // ia, ib, ic, op
        float4 P2 = pk2[src];        // dz, rbc, rba, -
        // --- exact conic-min-over-rect cull (per lane, its own gaussian) ---
        float dx0 = x0 - P0.x, dx1 = x1 - P0.x;
        float dy0 = y0 - P0.y, dy1 = y1 - P0.y;
        bool aabb = (dx0 <= P0.z) && (-dx1 <= P0.z) &&
                    (dy0 <= P0.w) && (-dy1 <= P0.w);
        bool inside = (dx0 <= 0.f) && (dx1 >= 0.f) && (dy0 <= 0.f) && (dy1 >= 0.f);
        float t, q0, q1, q2, q3;
        t  = fminf(fmaxf(P2.y * dx0, dy0), dy1);
        q0 = P1.x * dx0 * dx0 + t * (P1.z * t + 2.f * P1.y * dx0);
        t  = fminf(fmaxf(P2.y * dx1, dy0), dy1);
        q1 = P1.x * dx1 * dx1 + t * (P1.z * t + 2.f * P1.y * dx1);
        t  = fminf(fmaxf(P2.z * dy0, dx0), dx1);
        q2 = P1.z * dy0 * dy0 + t * (P1.x * t + 2.f * P1.y * dy0);
        t  = fminf(fmaxf(P2.z * dy1, dx0), dx1);
        q3 = P1.z * dy1 * dy1 + t * (P1.x * t + 2.f * P1.y * dy1);
        float mind2 = inside ? 0.f : fminf(fminf(q0, q1), fminf(q2, q3));
        unsigned long long mask = __ballot(inr && aabb && (mind2 <= 34.0f));
        if (!mask) continue;

        // --- survivor loop: wave-uniform SCALAR loads, prefetch depth 1 ---
        size_t sb = (size_t)bm * N + base;
        int su = __builtin_amdgcn_readfirstlane(__ffsll((long long)mask) - 1);
        mask &= mask - 1;
        float4 Q0 = pk0[sb + su];
        float4 Q1 = pk1[sb + su];
        float4 Q2 = pk2[sb + su];
        const float4* sv = (const float4*)(psem + (sb + su) * MAXC);
        float4 c0 = sv[0], c1 = sv[1], c2 = sv[2], c3 = sv[3];
        for (;;) {
            bool more = (mask != 0ull);
            int sn = more ? (__ffsll((long long)mask) - 1) : 0;
            mask &= mask - 1;
            sn = __builtin_amdgcn_readfirstlane(sn);
            float4 nQ0 = pk0[sb + sn];
            float4 nQ1 = pk1[sb + sn];
            float4 nQ2 = pk2[sb + sn];
            const float4* nsv = (const float4*)(psem + (sb + sn) * MAXC);
            float4 n0 = nsv[0], n1 = nsv[1], n2 = nsv[2], n3 = nsv[3];
            // process current survivor (Q*, c* are wave-uniform SGPR data)
            float dx = fxp - Q0.x, dy = fyp - Q0.y;
            float d2 = Q1.x*dx*dx + Q1.z*dy*dy + 2.0f*Q1.y*(dx*dy);
            float gvl = __expf(-0.5f * d2);
            float alpha = fminf(Q1.w * gvl, 0.99f);
            float w = T * alpha;
            T -= w;
            accD += w * Q2.x;
            accA += w;
            accS[0]  += w * c0.x;  accS[1]  += w * c0.y;
            accS[2]  += w * c0.z;  accS[3]  += w * c0.w;
            accS[4]  += w * c1.x;  accS[5]  += w * c1.y;
            accS[6]  += w * c1.z;  accS[7]  += w * c1.w;
            accS[8]  += w * c2.x;  accS[9]  += w * c2.y;
            accS[10] += w * c2.z;  accS[11] += w * c2.w;
            accS[12] += w * c3.x;  accS[13] += w * c3.y;
            accS[14] += w * c3.z;  accS[15] += w * c3.w;
            if (!more) break;
            Q0 = nQ0; Q1 = nQ1; Q2 = nQ2;
            c0 = n0; c1 = n1; c2 = n2; c3 = n3;
        }
    }

    // ---- two-pass segment combine: out_c = sum_w Tprefix(w) * acc_{w,c} ----
    int px = lane;
    int pxx = txi * 8 + (px & 7);
    int pyy = tyi * 8 + (px >> 3);
    bool inb = (pxx < W) && (pyy < H);
    size_t HW  = (size_t)H * W;
    size_t pix = (size_t)pyy * W + pxx;
    size_t BMHW = (size_t)BM * HW;

    // pass 1 rows: 0=T, 1=D, 2=A, 3..8=S0..S5
    float* my = comb + (wave * ROWS1) * 64 + lane;
    my[0 * 64] = T;
    my[1 * 64] = accD;
    my[2 * 64] = accA;
#pragma unroll
    for (int k = 0; k < 6; ++k) my[(3 + k) * 64] = accS[k];
    __syncthreads();

    float pre[NSEG];
    pre[0] = 1.f;
#pragma unroll
    for (int w = 1; w < NSEG; ++w)
        pre[w] = pre[w-1] * comb[((w-1) * ROWS1) * 64 + px];

    if (wave < 8) {   // pass 1 outputs: depth, sem0..5, alpha
        int row, outc;
        if (wave == 0)      { row = 1;        outc = 0; }       // depth
        else if (wave <= 6) { row = 2 + wave; outc = wave; }    // sem wave-1
        else                { row = 2;        outc = C + 1; }   // alpha
        float val = 0.f;
#pragma unroll
        for (int w = 0; w < NSEG; ++w)
            val += pre[w] * comb[(w * ROWS1 + row) * 64 + px];
        if (inb) {
            float* dst;
            if (outc == 0)      dst = out + (size_t)bm * HW + pix;
            else if (outc <= C) dst = out + BMHW + (size_t)bm * C * HW + (size_t)(outc-1) * HW + pix;
            else                dst = out + BMHW + BMHW * C + (size_t)bm * HW + pix;
            *dst = val;
        }
    }
    __syncthreads();   // pass-1 reads done before overwrite

    // pass 2 rows: 0..9 = S6..S15
    float* my2 = comb + (wave * ROWS2) * 64 + lane;
#pragma unroll
    for (int k = 0; k < 10; ++k) my2[k * 64] = accS[6 + k];
    __syncthreads();

    if (wave < 10) {   // sem6..15
        int k = wave;
        float val = 0.f;
#pragma unroll
        for (int w = 0; w < NSEG; ++w)
            val += pre[w] * comb[(w * ROWS2 + k) * 64 + px];
        if (inb) {
            int outc = 7 + k;   // sem index 6+k
            float* dst = out + BMHW + (size_t)bm * C * HW + (size_t)(outc-1) * HW + pix;
            *dst = val;
        }
    }
}

extern "C" void kernel_launch(void* const* d_in, const int* in_sizes, int n_in,
                              void* d_out, int out_size, void* d_ws, size_t ws_size,
                              hipStream_t stream) {
    const float* means  = (const float*)d_in[0];
    const float* scales = (const float*)d_in[1];
    const float* rots   = (const float*)d_in[2];
    const float* opac   = (const float*)d_in[3];
    const float* sem    = (const float*)d_in[4];
    const float* intr   = (const float*)d_in[5];
    const float* c2e    = (const float*)d_in[6];
    float* out = (float*)d_out;

    int B  = 1;
    int BM = in_sizes[6] / 16;         // cam2ego is (B,M,4,4)
    int M  = BM / B;
    int N  = in_sizes[0] / (3 * B);    // means (B,N,3)
    int C  = in_sizes[4] / (B * N);    // semantic_features (B,N,C)
    long HWl = (long)out_size / ((long)BM * (C + 2));
    int H = (int)(sqrt((double)HWl) + 0.5);
    int W = (int)(HWl / H);
    int ntx = (W + 7) / 8, nty = (H + 7) / 8;
    int ntiles = ntx * nty * BM;
    int nch64  = (N + 63) >> 6;

    float* ws = (float*)d_ws;
    size_t off = 0;
    size_t BMN  = (size_t)BM * N;
    int*   ikey = (int*)(ws + off); off += BMN;
    float* uu   = ws + off; off += BMN;
    float* vv   = ws + off; off += BMN;
    float* cia  = ws + off; off += BMN;
    float* cib  = ws + off; off += BMN;
    float* cic  = ws + off; off += BMN;
    float* cex  = ws + off; off += BMN;
    float* cey  = ws + off; off += BMN;
    float* crbc = ws + off; off += BMN;
    float* crba = ws + off; off += BMN;
    off = (off + 3) & ~(size_t)3;            // float4 alignment
    float4* pk0 = (float4*)(ws + off); off += BMN * 4;
    float4* pk1 = (float4*)(ws + off); off += BMN * 4;
    float4* pk2 = (float4*)(ws + off); off += BMN * 4;
    float* psem = ws + off; off += BMN * C;
    int* pcount = (int*)(ws + off); off += BM;

    int tot = BM * N;
    preprocess_kernel<<<(tot + 255) / 256, 256, 0, stream>>>(
        means, scales, rots, intr, c2e,
        ikey, uu, vv, cia, cib, cic, cex, cey, crbc, crba, B, M, N, W, H);

    rankpack_kernel<<<BM * nch64, 64, 0, stream>>>(
        ikey, uu, vv, cia, cib, cic, cex, cey, crbc, crba, opac, sem,
        pk0, pk1, pk2, psem, pcount, B, M, N, C);

    raster_kernel<<<ntiles, RTPB, 0, stream>>>(
        pk0, pk1, pk2, psem, pcount, out, BM, N, C, H, W, ntx, nty);
}

// Round 13
// 121.238 us; speedup vs baseline: 1.2012x; 1.1502x over previous
//
#include <hip/hip_runtime.h>
#include <cmath>

// SemanticDepthRasterizer — 4-kernel pipeline with tile binning.
// K1 preprocess: projection/conic (+inv(cam2ego) in double), cull extents.
// K2 rankpack:   O(N^2) rank-by-counting (stable argsort-by-z) + visible pack.
// K3 binlist:    per-tile ordered survivor lists (one block per tile, 8 waves
//                scan depth-contiguous ranges with exact conic-min-over-rect
//                cull, ballot-prefix append, block prefix concat). Removes the
//                16x-redundant scan that pinned raster at 41-50us (R8-R12).
// K4 raster:     one tile per block, 16 depth segments x 16 waves, processes
//                ONLY the survivor list via readlane broadcast (R8 structure),
//                two-pass prefix-transmittance combine.

#define MAXC   16     // semantic channels (C==16 here)
#define MAXBM  8
#define NSEG   16     // depth segments == waves per raster block
#define RTPB   (NSEG * 64)   // 1024 threads
#define BINW   8      // binlist waves per block
#define BINT   (BINW * 64)
#define MAXSEG 256    // max survivors per binlist wave (ceil(N/BINW), N<=2048)
#define ROWS1  9      // pass-1 rows: T,D,A,S0..S5
#define ROWS2  10     // pass-2 rows: S6..S15
#define INVIS_KEY 0x7FFFFFFF

__device__ __forceinline__ float rlf(float x, int l) {
    return __int_as_float(__builtin_amdgcn_readlane(__float_as_int(x), l));
}

// ---- 4x4 inverse (double, adjugate), top-3-rows result ----
__device__ void inv4x4_rows3(const float* __restrict__ src, float* __restrict__ Eout) {
    double m[16];
#pragma unroll
    for (int j = 0; j < 16; ++j) m[j] = (double)src[j];
    double inv[16];
    inv[0]  =  m[5]*m[10]*m[15] - m[5]*m[11]*m[14] - m[9]*m[6]*m[15] + m[9]*m[7]*m[14] + m[13]*m[6]*m[11] - m[13]*m[7]*m[10];
    inv[4]  = -m[4]*m[10]*m[15] + m[4]*m[11]*m[14] + m[8]*m[6]*m[15] - m[8]*m[7]*m[14] - m[12]*m[6]*m[11] + m[12]*m[7]*m[10];
    inv[8]  =  m[4]*m[9]*m[15]  - m[4]*m[11]*m[13] - m[8]*m[5]*m[15] + m[8]*m[7]*m[13] + m[12]*m[5]*m[11] - m[12]*m[7]*m[9];
    inv[12] = -m[4]*m[9]*m[14]  + m[4]*m[10]*m[13] + m[8]*m[5]*m[14] - m[8]*m[6]*m[13] - m[12]*m[5]*m[10] + m[12]*m[6]*m[9];
    inv[1]  = -m[1]*m[10]*m[15] + m[1]*m[11]*m[14] + m[9]*m[2]*m[15] - m[9]*m[3]*m[14] - m[13]*m[2]*m[11] + m[13]*m[3]*m[10];
    inv[5]  =  m[0]*m[10]*m[15] - m[0]*m[11]*m[14] - m[8]*m[2]*m[15] + m[8]*m[3]*m[14] + m[12]*m[2]*m[11] - m[12]*m[3]*m[10];
    inv[9]  = -m[0]*m[9]*m[15]  + m[0]*m[11]*m[13] + m[8]*m[1]*m[15] - m[8]*m[3]*m[13] - m[12]*m[1]*m[11] + m[12]*m[3]*m[9];
    inv[13] =  m[0]*m[9]*m[14]  - m[0]*m[10]*m[13] - m[8]*m[1]*m[14] + m[8]*m[2]*m[13] + m[12]*m[1]*m[10] - m[12]*m[2]*m[9];
    inv[2]  =  m[1]*m[6]*m[15]  - m[1]*m[7]*m[14]  - m[5]*m[2]*m[15] + m[5]*m[3]*m[14] + m[13]*m[2]*m[7]  - m[13]*m[3]*m[6];
    inv[6]  = -m[0]*m[6]*m[15]  + m[0]*m[7]*m[14]  + m[4]*m[2]*m[15] - m[4]*m[3]*m[14] - m[12]*m[2]*m[7]  + m[12]*m[3]*m[6];
    inv[10] =  m[0]*m[5]*m[15]  - m[0]*m[7]*m[13]  - m[4]*m[1]*m[15] + m[4]*m[3]*m[13] + m[12]*m[1]*m[7]  - m[12]*m[3]*m[5];
    inv[14] = -m[0]*m[5]*m[14]  + m[0]*m[6]*m[13]  + m[4]*m[1]*m[14] - m[4]*m[2]*m[13] - m[12]*m[1]*m[6]  + m[12]*m[2]*m[5];
    inv[3]  = -m[1]*m[6]*m[11]  + m[1]*m[7]*m[10]  + m[5]*m[2]*m[11] - m[5]*m[3]*m[10] - m[9]*m[2]*m[7]   + m[9]*m[3]*m[6];
    inv[7]  =  m[0]*m[6]*m[11]  - m[0]*m[7]*m[10]  - m[4]*m[2]*m[11] + m[4]*m[3]*m[10] + m[8]*m[2]*m[7]   - m[8]*m[3]*m[6];
    inv[11] = -m[0]*m[5]*m[11]  + m[0]*m[7]*m[9]   + m[4]*m[1]*m[11] - m[4]*m[3]*m[9]  - m[8]*m[1]*m[7]   + m[8]*m[3]*m[5];
    inv[15] =  m[0]*m[5]*m[10]  - m[0]*m[6]*m[9]   - m[4]*m[1]*m[10] + m[4]*m[2]*m[9]  + m[8]*m[1]*m[6]   - m[8]*m[2]*m[5];
    double det = m[0]*inv[0] + m[1]*inv[4] + m[2]*inv[8] + m[3]*inv[12];
    double rdet = 1.0 / det;
#pragma unroll
    for (int r = 0; r < 3; ++r)
#pragma unroll
        for (int c = 0; c < 4; ++c)
            Eout[r * 4 + c] = (float)(inv[r * 4 + c] * rdet);
}

// ---------------- K1: per-gaussian projection + conic ----------------
__global__ __launch_bounds__(256) void preprocess_kernel(
    const float* __restrict__ means, const float* __restrict__ scales,
    const float* __restrict__ rots,  const float* __restrict__ intr,
    const float* __restrict__ cam2ego,
    int* __restrict__ ikey, float* __restrict__ uu, float* __restrict__ vv,
    float* __restrict__ cia, float* __restrict__ cib, float* __restrict__ cic,
    float* __restrict__ cex, float* __restrict__ cey,
    float* __restrict__ crbc, float* __restrict__ crba,
    int B, int M, int N, int W, int H)
{
    __shared__ float Esh[MAXBM * 12];
    int BM = B * M;
    if (threadIdx.x < (unsigned)BM)
        inv4x4_rows3(cam2ego + (size_t)threadIdx.x * 16, Esh + threadIdx.x * 12);
    __syncthreads();

    int gid = blockIdx.x * 256 + threadIdx.x;
    if (gid >= BM * N) return;
    int bm = gid / N;
    int n  = gid - bm * N;
    int b  = bm / M;
    const float* Ep = Esh + bm * 12;
    const float* mp = means + ((size_t)b * N + n) * 3;
    float mx = mp[0], my = mp[1], mz = mp[2];
    float x_c = Ep[0]*mx + Ep[1]*my + Ep[2]*mz  + Ep[3];
    float y_c = Ep[4]*mx + Ep[5]*my + Ep[6]*mz  + Ep[7];
    float z   = Ep[8]*mx + Ep[9]*my + Ep[10]*mz + Ep[11];
    const float* K = intr + (size_t)bm * 16;
    float fx = K[0], fy = K[5], cx = K[2], cy = K[6];
    float zs = fmaxf(z, 1e-4f);
    float u = x_c / zs * fx + cx;
    float v = y_c / zs * fy + cy;
    const float* qp = rots + ((size_t)b * N + n) * 4;
    float qw = qp[0], qx = qp[1], qy = qp[2], qz = qp[3];
    float qn = sqrtf(qw*qw + qx*qx + qy*qy + qz*qz);
    qw /= qn; qx /= qn; qy /= qn; qz /= qn;
    float R00 = 1.f - 2.f*(qy*qy + qz*qz), R01 = 2.f*(qx*qy - qz*qw), R02 = 2.f*(qx*qz + qy*qw);
    float R10 = 2.f*(qx*qy + qz*qw), R11 = 1.f - 2.f*(qx*qx + qz*qz), R12 = 2.f*(qy*qz - qx*qw);
    float R20 = 2.f*(qx*qz - qy*qw), R21 = 2.f*(qy*qz + qx*qw), R22 = 1.f - 2.f*(qx*qx + qy*qy);
    const float* sp = scales + ((size_t)b * N + n) * 3;
    float s0 = sp[0]*sp[0], s1 = sp[1]*sp[1], s2 = sp[2]*sp[2];
    float S00 = R00*R00*s0 + R01*R01*s1 + R02*R02*s2;
    float S01 = R00*R10*s0 + R01*R11*s1 + R02*R12*s2;
    float S02 = R00*R20*s0 + R01*R21*s1 + R02*R22*s2;
    float S11 = R10*R10*s0 + R11*R11*s1 + R12*R12*s2;
    float S12 = R10*R20*s0 + R11*R21*s1 + R12*R22*s2;
    float S22 = R20*R20*s0 + R21*R21*s1 + R22*R22*s2;
    float W00 = Ep[0], W01 = Ep[1], W02 = Ep[2];
    float W10 = Ep[4], W11 = Ep[5], W12 = Ep[6];
    float W20 = Ep[8], W21 = Ep[9], W22 = Ep[10];
    float A00 = W00*S00 + W01*S01 + W02*S02;
    float A01 = W00*S01 + W01*S11 + W02*S12;
    float A02 = W00*S02 + W01*S12 + W02*S22;
    float A10 = W10*S00 + W11*S01 + W12*S02;
    float A11 = W10*S01 + W11*S11 + W12*S12;
    float A12 = W10*S02 + W11*S12 + W12*S22;
    float A20 = W20*S00 + W21*S01 + W22*S02;
    float A21 = W20*S01 + W21*S11 + W22*S12;
    float A22 = W20*S02 + W21*S12 + W22*S22;
    float Sc00 = A00*W00 + A01*W01 + A02*W02;
    float Sc01 = A00*W10 + A01*W11 + A02*W12;
    float Sc02 = A00*W20 + A01*W21 + A02*W22;
    float Sc11 = A10*W10 + A11*W11 + A12*W12;
    float Sc12 = A10*W20 + A11*W21 + A12*W22;
    float Sc22 = A20*W20 + A21*W21 + A22*W22;
    float j00 = fx / zs,  j02 = -fx * x_c / (zs * zs);
    float j11 = fy / zs,  j12 = -fy * y_c / (zs * zs);
    float c00 = j00*j00*Sc00 + 2.f*j00*j02*Sc02 + j02*j02*Sc22;
    float c01 = j00*(Sc01*j11 + Sc02*j12) + j02*(Sc12*j11 + Sc22*j12);
    float c11 = j11*j11*Sc11 + 2.f*j11*j12*Sc12 + j12*j12*Sc22;
    float a  = fmaxf(c00, 0.3f);
    float cc = fmaxf(c11, 0.3f);
    float bb = c01;
    float det = a * cc - bb * bb;
    bool valid = (z > 0.01f) && (det > 1e-8f);
    float det_s = (det > 1e-8f) ? det : 1.0f;
    float ia = cc / det_s, ib = -bb / det_s, ic = a / det_s;
    uu[gid] = u;  vv[gid] = v;
    cia[gid] = ia;  cib[gid] = ib;  cic[gid] = ic;
    cex[gid] = sqrtf(34.0f * a);    // ellipse {d2<=34} AABB half-extents
    cey[gid] = sqrtf(34.0f * cc);
    crbc[gid] = -bb / a;            // edge-min ratios (div-free cull)
    crba[gid] = -bb / cc;
    bool visible = valid && (z > 0.1f) &&
                   (u >= 0.f) && (u < (float)W) && (v >= 0.f) && (v < (float)H);
    ikey[gid] = visible ? __float_as_int(z) : INVIS_KEY;
}

// -- K2: rank one 64-i chunk per block (stable argsort by z) + pack --
__global__ __launch_bounds__(64) void rankpack_kernel(
    const int* __restrict__ ikey,
    const float* __restrict__ uu, const float* __restrict__ vv,
    const float* __restrict__ cia, const float* __restrict__ cib,
    const float* __restrict__ cic, const float* __restrict__ cex,
    const float* __restrict__ cey, const float* __restrict__ crbc,
    const float* __restrict__ crba,
    const float* __restrict__ opac, const float* __restrict__ sem,
    float4* __restrict__ pk0, float4* __restrict__ pk1,
    float4* __restrict__ pk2,
    float* __restrict__ psem, int* __restrict__ pcount,
    int B, int M, int N, int C)
{
    int lane  = threadIdx.x & 63;
    int nch64 = (N + 63) >> 6;
    int chunk = blockIdx.x;
    int bm = chunk / nch64;
    int cl = chunk - bm * nch64;
    int i  = (cl << 6) + lane;
    const int* kb = ikey + (size_t)bm * N;
    int ki  = (i < N) ? kb[i] : INVIS_KEY;
    int kip = ki + 1;
    int rank = 0, tot = 0;
    int kj = (lane < N) ? kb[lane] : INVIS_KEY;
    for (int jc = 0; jc < nch64; ++jc) {
        int kcur = kj;
        if (jc + 1 < nch64) {
            int jn = ((jc + 1) << 6) + lane;
            kj = (jn < N) ? kb[jn] : INVIS_KEY;
        }
        tot += (int)__popcll(__ballot(kcur != INVIS_KEY));
        if (jc < cl) {
#pragma unroll
            for (int gg = 0; gg < 64; ++gg)
                rank += (__builtin_amdgcn_readlane(kcur, gg) < kip);
        } else if (jc > cl) {
#pragma unroll
            for (int gg = 0; gg < 64; ++gg)
                rank += (__builtin_amdgcn_readlane(kcur, gg) < ki);
        } else {
#pragma unroll
            for (int gg = 0; gg < 64; ++gg) {
                int kk = (gg < lane) ? kip : ki;
                rank += (__builtin_amdgcn_readlane(kcur, gg) < kk);
            }
        }
    }
    if (cl == 0 && lane == 0) pcount[bm] = tot;
    if (i < N && ki != INVIS_KEY) {
        int b = bm / M;
        size_t src = (size_t)bm * N + i;
        size_t dst = (size_t)bm * N + rank;
        float z = __int_as_float(ki);
        pk0[dst] = make_float4(uu[src], vv[src], cex[src], cey[src]);
        pk1[dst] = make_float4(cia[src], cib[src], cic[src],
                               opac[(size_t)b * N + i]);
        pk2[dst] = make_float4(fminf(fmaxf(z, 0.1f), 100.0f),
                               crbc[src], crba[src], 0.f);
        const float* spc = sem + ((size_t)b * N + i) * C;
        float* dpc = psem + dst * C;
        int c4 = C & ~3;
        for (int q = 0; q < c4; q += 4)
            *(float4*)(dpc + q) = *(const float4*)(spc + q);
        for (int q = c4; q < C; ++q) dpc[q] = spc[q];
    }
}

// ---- K3: per-tile ordered survivor list (one block per tile, 8 waves) ----
__global__ __launch_bounds__(BINT) void binlist_kernel(
    const float4* __restrict__ pk0, const float4* __restrict__ pk1,
    const float4* __restrict__ pk2, const int* __restrict__ pcount,
    int* __restrict__ list, int* __restrict__ tilecount,
    int BM, int N, int ntx, int nty)
{
    __shared__ int stage[BINW][MAXSEG];
    __shared__ int wcnt[BINW];
    int wave = threadIdx.x >> 6;
    int lane = threadIdx.x & 63;
    int tile = blockIdx.x;
    int tpv = ntx * nty;
    int bm  = tile / tpv;
    int rem = tile - bm * tpv;
    int tyi = rem / ntx;
    int txi = rem - tyi * ntx;
    float x0 = (float)(txi * 8),     y0 = (float)(tyi * 8);
    float x1 = (float)(txi * 8 + 7), y1 = (float)(tyi * 8 + 7);

    int cnt = pcount[bm];
    int seg = (cnt + BINW - 1) / BINW;
    int gs = wave * seg;
    int ge = min(gs + seg, cnt);

    int nlocal = 0;
    for (int base = gs; base < ge; base += 64) {
        int g = base + lane;
        bool inr = g < ge;
        int gc = inr ? g : (ge - 1);
        size_t src = (size_t)bm * N + gc;
        float4 P0 = pk0[src];
        float4 P1 = pk1[src];
        float4 P2 = pk2[src];
        float dx0 = x0 - P0.x, dx1 = x1 - P0.x;
        float dy0 = y0 - P0.y, dy1 = y1 - P0.y;
        bool aabb = (dx0 <= P0.z) && (-dx1 <= P0.z) &&
                    (dy0 <= P0.w) && (-dy1 <= P0.w);
        bool inside = (dx0 <= 0.f) && (dx1 >= 0.f) && (dy0 <= 0.f) && (dy1 >= 0.f);
        float t, q0, q1, q2, q3;
        t  = fminf(fmaxf(P2.y * dx0, dy0), dy1);
        q0 = P1.x * dx0 * dx0 + t * (P1.z * t + 2.f * P1.y * dx0);
        t  = fminf(fmaxf(P2.y * dx1, dy0), dy1);
        q1 = P1.x * dx1 * dx1 + t * (P1.z * t + 2.f * P1.y * dx1);
        t  = fminf(fmaxf(P2.z * dy0, dx0), dx1);
        q2 = P1.z * dy0 * dy0 + t * (P1.x * t + 2.f * P1.y * dy0);
        t  = fminf(fmaxf(P2.z * dy1, dx0), dx1);
        q3 = P1.z * dy1 * dy1 + t * (P1.x * t + 2.f * P1.y * dy1);
        float mind2 = inside ? 0.f : fminf(fminf(q0, q1), fminf(q2, q3));
        unsigned long long mask = __ballot(inr && aabb && (mind2 <= 34.0f));
        // ordered append: lane-order == depth order within chunk
        if ((mask >> lane) & 1ull) {
            int pos = nlocal + (int)__popcll(mask & ((1ull << lane) - 1ull));
            stage[wave][pos] = g;
        }
        nlocal += (int)__popcll(mask);
    }
    if (lane == 0) wcnt[wave] = nlocal;
    __syncthreads();
    int offs = 0, total = 0;
    for (int w = 0; w < BINW; ++w) {
        if (w < wave) offs += wcnt[w];
        total += wcnt[w];
    }
    int* dst = list + (size_t)tile * N;
    for (int i = lane; i < nlocal; i += 64) dst[offs + i] = stage[wave][i];
    if (threadIdx.x == 0) tilecount[tile] = total;
}

// ---- K4: one tile per block, 16 segments x 16 waves, list-driven ----
__global__ __launch_bounds__(RTPB) void raster_kernel(
    const float4* __restrict__ pk0, const float4* __restrict__ pk1,
    const float4* __restrict__ pk2,
    const float* __restrict__ psem,
    const int* __restrict__ list, const int* __restrict__ tilecount,
    float* __restrict__ out,
    int BM, int N, int C, int H, int W, int ntx, int nty)
{
    __shared__ float comb[NSEG * ROWS2 * 64];   // 40 KB; pass1 uses ROWS1 rows
    int wave = threadIdx.x >> 6;
    int lane = threadIdx.x & 63;
    int tile = blockIdx.x;
    int tpv = ntx * nty;
    int bm  = tile / tpv;
    int rem = tile - bm * tpv;
    int tyi = rem / ntx;
    int txi = rem - tyi * ntx;
    int lx = lane & 7, ly = lane >> 3;
    float fxp = (float)(txi * 8 + lx), fyp = (float)(tyi * 8 + ly);

    int cnt = tilecount[tile];
    int seg = (cnt + NSEG - 1) / NSEG;
    int gs = wave * seg;
    int ge = min(gs + seg, cnt);

    float T = 1.0f, accA = 0.f, accD = 0.f;
    float accS[MAXC];
#pragma unroll
    for (int q = 0; q < MAXC; ++q) accS[q] = 0.f;

    const int* tl = list + (size_t)tile * N;
    for (int base = gs; base < ge; base += 64) {
        int g = base + lane;
        bool inr = g < ge;
        int idx = tl[inr ? g : (ge - 1)];
        size_t src = (size_t)bm * N + idx;
        float4 P0 = pk0[src];        // u, v, -, -
        float4 P1 = pk1[src];        // ia, ib, ic, op
        float4 P2 = pk2[src];        // dz, -, -, -
        float sf[MAXC];
        {
            const float4* spc = (const float4*)(psem + src * MAXC);
#pragma unroll
            for (int q = 0; q < MAXC / 4; ++q) {
                float4 f = spc[q];
                sf[q*4+0] = f.x; sf[q*4+1] = f.y; sf[q*4+2] = f.z; sf[q*4+3] = f.w;
            }
        }
        int nev = min(64, ge - base);
        for (int gg = 0; gg < nev; ++gg) {   // list order = depth order
            float u  = rlf(P0.x, gg), v  = rlf(P0.y, gg);
            float ia = rlf(P1.x, gg), ib = rlf(P1.y, gg), ic = rlf(P1.z, gg);
            float dx = fxp - u, dy = fyp - v;
            float d2 = ia*dx*dx + ic*dy*dy + 2.0f*ib*(dx*dy);
            float gvl = __expf(-0.5f * d2);
            float alpha = fminf(rlf(P1.w, gg) * gvl, 0.99f);
            float w = T * alpha;
            T -= w;
            accD += w * rlf(P2.x, gg);
            accA += w;
#pragma unroll
            for (int ch = 0; ch < MAXC; ++ch) accS[ch] += w * rlf(sf[ch], gg);
        }
    }

    // ---- two-pass segment combine: out_c = sum_w Tprefix(w) * acc_{w,c} ----
    int px = lane;
    int pxx = txi * 8 + (px & 7);
    int pyy = tyi * 8 + (px >> 3);
    bool inb = (pxx < W) && (pyy < H);
    size_t HW  = (size_t)H * W;
    size_t pix = (size_t)pyy * W + pxx;
    size_t BMHW = (size_t)BM * HW;

    // pass 1 rows: 0=T, 1=D, 2=A, 3..8=S0..S5
    float* my = comb + (wave * ROWS1) * 64 + lane;
    my[0 * 64] = T;
    my[1 * 64] = accD;
    my[2 * 64] = accA;
#pragma unroll
    for (int k = 0; k < 6; ++k) my[(3 + k) * 64] = accS[k];
    __syncthreads();

    float pre[NSEG];
    pre[0] = 1.f;
#pragma unroll
    for (int w = 1; w < NSEG; ++w)
        pre[w] = pre[w-1] * comb[((w-1) * ROWS1) * 64 + px];

    if (wave < 8) {   // pass 1 outputs: depth, sem0..5, alpha
        int row, outc;
        if (wave == 0)      { row = 1;        outc = 0; }       // depth
        else if (wave <= 6) { row = 2 + wave; outc = wave; }    // sem wave-1
        else                { row = 2;        outc = C + 1; }   // alpha
        float val = 0.f;
#pragma unroll
        for (int w = 0; w < NSEG; ++w)
            val += pre[w] * comb[(w * ROWS1 + row) * 64 + px];
        if (inb) {
            float* dst;
            if (outc == 0)      dst = out + (size_t)bm * HW + pix;
            else if (outc <= C) dst = out + BMHW + (size_t)bm * C * HW + (size_t)(outc-1) * HW + pix;
            else                dst = out + BMHW + BMHW * C + (size_t)bm * HW + pix;
            *dst = val;
        }
    }
    __syncthreads();   // pass-1 reads done before overwrite

    // pass 2 rows: 0..9 = S6..S15
    float* my2 = comb + (wave * ROWS2) * 64 + lane;
#pragma unroll
    for (int k = 0; k < 10; ++k) my2[k * 64] = accS[6 + k];
    __syncthreads();

    if (wave < 10) {   // sem6..15
        int k = wave;
        float val = 0.f;
#pragma unroll
        for (int w = 0; w < NSEG; ++w)
            val += pre[w] * comb[(w * ROWS2 + k) * 64 + px];
        if (inb) {
            int outc = 7 + k;   // sem index 6+k
            float* dst = out + BMHW + (size_t)bm * C * HW + (size_t)(outc-1) * HW + pix;
            *dst = val;
        }
    }
}

extern "C" void kernel_launch(void* const* d_in, const int* in_sizes, int n_in,
                              void* d_out, int out_size, void* d_ws, size_t ws_size,
                              hipStream_t stream) {
    const float* means  = (const float*)d_in[0];
    const float* scales = (const float*)d_in[1];
    const float* rots   = (const float*)d_in[2];
    const float* opac   = (const float*)d_in[3];
    const float* sem    = (const float*)d_in[4];
    const float* intr   = (const float*)d_in[5];
    const float* c2e    = (const float*)d_in[6];
    float* out = (float*)d_out;

    int B  = 1;
    int BM = in_sizes[6] / 16;         // cam2ego is (B,M,4,4)
    int M  = BM / B;
    int N  = in_sizes[0] / (3 * B);    // means (B,N,3)
    int C  = in_sizes[4] / (B * N);    // semantic_features (B,N,C)
    long HWl = (long)out_size / ((long)BM * (C + 2));
    int H = (int)(sqrt((double)HWl) + 0.5);
    int W = (int)(HWl / H);
    int ntx = (W + 7) / 8, nty = (H + 7) / 8;
    int ntiles = ntx * nty * BM;
    int nch64  = (N + 63) >> 6;

    float* ws = (float*)d_ws;
    size_t off = 0;
    size_t BMN  = (size_t)BM * N;
    int*   ikey = (int*)(ws + off); off += BMN;
    float* uu   = ws + off; off += BMN;
    float* vv   = ws + off; off += BMN;
    float* cia  = ws + off; off += BMN;
    float* cib  = ws + off; off += BMN;
    float* cic  = ws + off; off += BMN;
    float* cex  = ws + off; off += BMN;
    float* cey  = ws + off; off += BMN;
    float* crbc = ws + off; off += BMN;
    float* crba = ws + off; off += BMN;
    off = (off + 3) & ~(size_t)3;            // float4 alignment
    float4* pk0 = (float4*)(ws + off); off += BMN * 4;
    float4* pk1 = (float4*)(ws + off); off += BMN * 4;
    float4* pk2 = (float4*)(ws + off); off += BMN * 4;
    float* psem = ws + off; off += BMN * C;
    int* pcount = (int*)(ws + off); off += BM;
    int* list   = (int*)(ws + off); off += (size_t)ntiles * N;
    int* tcnt   = (int*)(ws + off); off += ntiles;

    int tot = BM * N;
    preprocess_kernel<<<(tot + 255) / 256, 256, 0, stream>>>(
        means, scales, rots, intr, c2e,
        ikey, uu, vv, cia, cib, cic, cex, cey, crbc, crba, B, M, N, W, H);

    rankpack_kernel<<<BM * nch64, 64, 0, stream>>>(
        ikey, uu, vv, cia, cib, cic, cex, cey, crbc, crba, opac, sem,
        pk0, pk1, pk2, psem, pcount, B, M, N, C);

    binlist_kernel<<<ntiles, BINT, 0, stream>>>(
        pk0, pk1, pk2, pcount, list, tcnt, BM, N, ntx, nty);

    raster_kernel<<<ntiles, RTPB, 0, stream>>>(
        pk0, pk1, pk2, psem, list, tcnt, out, BM, N, C, H, W, ntx, nty);
}

// Round 14
// 112.027 us; speedup vs baseline: 1.2999x; 1.0822x over previous
//
#include <hip/hip_runtime.h>
#include <cmath>

// SemanticDepthRasterizer — 3-kernel pipeline, binning fused into raster.
// K1 preprocess: projection/conic (+inv(cam2ego) in double), cull extents.
// K2 rankpack:   O(N^2) rank-by-counting (stable argsort-by-z) + visible pack;
//                j-loop split across 4 waves + LDS reduce (4x less serial depth).
// K3 raster:     one tile per block, 16 waves. Phase 1: all waves scan
//                depth-contiguous ranges with exact conic-min-over-rect cull,
//                ballot-append into LDS staging, flatten in depth order.
//                Phase 2: waves process equal slices of the LDS survivor list
//                via readlane broadcast. Phase 3: two-pass prefix-transmittance
//                combine (comb buffer ALIASES the bin staging; barrier-separated).
// Harness floor (measured R13): 40us fillBuffer re-poison of the 268MB ws +
// memsets/restores/gaps — outside kernel control.

#define MAXC   16     // semantic channels (C==16 here)
#define MAXBM  8
#define NSEG   16     // waves per raster block == depth segments
#define RTPB   (NSEG * 64)   // 1024 threads
#define SEGCAP 128    // max survivors per scan wave = ceil(N/NSEG), N<=2048
#define ROWS1  9      // pass-1 rows: T,D,A,S0..S5
#define ROWS2  10     // pass-2 rows: S6..S15
#define RPW    4      // rankpack waves per block
#define INVIS_KEY 0x7FFFFFFF

__device__ __forceinline__ float rlf(float x, int l) {
    return __int_as_float(__builtin_amdgcn_readlane(__float_as_int(x), l));
}

// ---- 4x4 inverse (double, adjugate), top-3-rows result ----
__device__ void inv4x4_rows3(const float* __restrict__ src, float* __restrict__ Eout) {
    double m[16];
#pragma unroll
    for (int j = 0; j < 16; ++j) m[j] = (double)src[j];
    double inv[16];
    inv[0]  =  m[5]*m[10]*m[15] - m[5]*m[11]*m[14] - m[9]*m[6]*m[15] + m[9]*m[7]*m[14] + m[13]*m[6]*m[11] - m[13]*m[7]*m[10];
    inv[4]  = -m[4]*m[10]*m[15] + m[4]*m[11]*m[14] + m[8]*m[6]*m[15] - m[8]*m[7]*m[14] - m[12]*m[6]*m[11] + m[12]*m[7]*m[10];
    inv[8]  =  m[4]*m[9]*m[15]  - m[4]*m[11]*m[13] - m[8]*m[5]*m[15] + m[8]*m[7]*m[13] + m[12]*m[5]*m[11] - m[12]*m[7]*m[9];
    inv[12] = -m[4]*m[9]*m[14]  + m[4]*m[10]*m[13] + m[8]*m[5]*m[14] - m[8]*m[6]*m[13] - m[12]*m[5]*m[10] + m[12]*m[6]*m[9];
    inv[1]  = -m[1]*m[10]*m[15] + m[1]*m[11]*m[14] + m[9]*m[2]*m[15] - m[9]*m[3]*m[14] - m[13]*m[2]*m[11] + m[13]*m[3]*m[10];
    inv[5]  =  m[0]*m[10]*m[15] - m[0]*m[11]*m[14] - m[8]*m[2]*m[15] + m[8]*m[3]*m[14] + m[12]*m[2]*m[11] - m[12]*m[3]*m[10];
    inv[9]  = -m[0]*m[9]*m[15]  + m[0]*m[11]*m[13] + m[8]*m[1]*m[15] - m[8]*m[3]*m[13] - m[12]*m[1]*m[11] + m[12]*m[3]*m[9];
    inv[13] =  m[0]*m[9]*m[14]  - m[0]*m[10]*m[13] - m[8]*m[1]*m[14] + m[8]*m[2]*m[13] + m[12]*m[1]*m[10] - m[12]*m[2]*m[9];
    inv[2]  =  m[1]*m[6]*m[15]  - m[1]*m[7]*m[14]  - m[5]*m[2]*m[15] + m[5]*m[3]*m[14] + m[13]*m[2]*m[7]  - m[13]*m[3]*m[6];
    inv[6]  = -m[0]*m[6]*m[15]  + m[0]*m[7]*m[14]  + m[4]*m[2]*m[15] - m[4]*m[3]*m[14] - m[12]*m[2]*m[7]  + m[12]*m[3]*m[6];
    inv[10] =  m[0]*m[5]*m[15]  - m[0]*m[7]*m[13]  - m[4]*m[1]*m[15] + m[4]*m[3]*m[13] + m[12]*m[1]*m[7]  - m[12]*m[3]*m[5];
    inv[14] = -m[0]*m[5]*m[14]  + m[0]*m[6]*m[13]  + m[4]*m[1]*m[14] - m[4]*m[2]*m[13] - m[12]*m[1]*m[6]  + m[12]*m[2]*m[5];
    inv[3]  = -m[1]*m[6]*m[11]  + m[1]*m[7]*m[10]  + m[5]*m[2]*m[11] - m[5]*m[3]*m[10] - m[9]*m[2]*m[7]   + m[9]*m[3]*m[6];
    inv[7]  =  m[0]*m[6]*m[11]  - m[0]*m[7]*m[10]  - m[4]*m[2]*m[11] + m[4]*m[3]*m[10] + m[8]*m[2]*m[7]   - m[8]*m[3]*m[6];
    inv[11] = -m[0]*m[5]*m[11]  + m[0]*m[7]*m[9]   + m[4]*m[1]*m[11] - m[4]*m[3]*m[9]  - m[8]*m[1]*m[7]   + m[8]*m[3]*m[5];
    inv[15] =  m[0]*m[5]*m[10]  - m[0]*m[6]*m[9]   - m[4]*m[1]*m[10] + m[4]*m[2]*m[9]  + m[8]*m[1]*m[6]   - m[8]*m[2]*m[5];
    double det = m[0]*inv[0] + m[1]*inv[4] + m[2]*inv[8] + m[3]*inv[12];
    double rdet = 1.0 / det;
#pragma unroll
    for (int r = 0; r < 3; ++r)
#pragma unroll
        for (int c = 0; c < 4; ++c)
            Eout[r * 4 + c] = (float)(inv[r * 4 + c] * rdet);
}

// ---------------- K1: per-gaussian projection + conic ----------------
__global__ __launch_bounds__(256) void preprocess_kernel(
    const float* __restrict__ means, const float* __restrict__ scales,
    const float* __restrict__ rots,  const float* __restrict__ intr,
    const float* __restrict__ cam2ego,
    int* __restrict__ ikey, float* __restrict__ uu, float* __restrict__ vv,
    float* __restrict__ cia, float* __restrict__ cib, float* __restrict__ cic,
    float* __restrict__ cex, float* __restrict__ cey,
    float* __restrict__ crbc, float* __restrict__ crba,
    int B, int M, int N, int W, int H)
{
    __shared__ float Esh[MAXBM * 12];
    int BM = B * M;
    if (threadIdx.x < (unsigned)BM)
        inv4x4_rows3(cam2ego + (size_t)threadIdx.x * 16, Esh + threadIdx.x * 12);
    __syncthreads();

    int gid = blockIdx.x * 256 + threadIdx.x;
    if (gid >= BM * N) return;
    int bm = gid / N;
    int n  = gid - bm * N;
    int b  = bm / M;
    const float* Ep = Esh + bm * 12;
    const float* mp = means + ((size_t)b * N + n) * 3;
    float mx = mp[0], my = mp[1], mz = mp[2];
    float x_c = Ep[0]*mx + Ep[1]*my + Ep[2]*mz  + Ep[3];
    float y_c = Ep[4]*mx + Ep[5]*my + Ep[6]*mz  + Ep[7];
    float z   = Ep[8]*mx + Ep[9]*my + Ep[10]*mz + Ep[11];
    const float* K = intr + (size_t)bm * 16;
    float fx = K[0], fy = K[5], cx = K[2], cy = K[6];
    float zs = fmaxf(z, 1e-4f);
    float u = x_c / zs * fx + cx;
    float v = y_c / zs * fy + cy;
    const float* qp = rots + ((size_t)b * N + n) * 4;
    float qw = qp[0], qx = qp[1], qy = qp[2], qz = qp[3];
    float qn = sqrtf(qw*qw + qx*qx + qy*qy + qz*qz);
    qw /= qn; qx /= qn; qy /= qn; qz /= qn;
    float R00 = 1.f - 2.f*(qy*qy + qz*qz), R01 = 2.f*(qx*qy - qz*qw), R02 = 2.f*(qx*qz + qy*qw);
    float R10 = 2.f*(qx*qy + qz*qw), R11 = 1.f - 2.f*(qx*qx + qz*qz), R12 = 2.f*(qy*qz - qx*qw);
    float R20 = 2.f*(qx*qz - qy*qw), R21 = 2.f*(qy*qz + qx*qw), R22 = 1.f - 2.f*(qx*qx + qy*qy);
    const float* sp = scales + ((size_t)b * N + n) * 3;
    float s0 = sp[0]*sp[0], s1 = sp[1]*sp[1], s2 = sp[2]*sp[2];
    float S00 = R00*R00*s0 + R01*R01*s1 + R02*R02*s2;
    float S01 = R00*R10*s0 + R01*R11*s1 + R02*R12*s2;
    float S02 = R00*R20*s0 + R01*R21*s1 + R02*R22*s2;
    float S11 = R10*R10*s0 + R11*R11*s1 + R12*R12*s2;
    float S12 = R10*R20*s0 + R11*R21*s1 + R12*R22*s2;
    float S22 = R20*R20*s0 + R21*R21*s1 + R22*R22*s2;
    float W00 = Ep[0], W01 = Ep[1], W02 = Ep[2];
    float W10 = Ep[4], W11 = Ep[5], W12 = Ep[6];
    float W20 = Ep[8], W21 = Ep[9], W22 = Ep[10];
    float A00 = W00*S00 + W01*S01 + W02*S02;
    float A01 = W00*S01 + W01*S11 + W02*S12;
    float A02 = W00*S02 + W01*S12 + W02*S22;
    float A10 = W10*S00 + W11*S01 + W12*S02;
    float A11 = W10*S01 + W11*S11 + W12*S12;
    float A12 = W10*S02 + W11*S12 + W12*S22;
    float A20 = W20*S00 + W21*S01 + W22*S02;
    float A21 = W20*S01 + W21*S11 + W22*S12;
    float A22 = W20*S02 + W21*S12 + W22*S22;
    float Sc00 = A00*W00 + A01*W01 + A02*W02;
    float Sc01 = A00*W10 + A01*W11 + A02*W12;
    float Sc02 = A00*W20 + A01*W21 + A02*W22;
    float Sc11 = A10*W10 + A11*W11 + A12*W12;
    float Sc12 = A10*W20 + A11*W21 + A12*W22;
    float Sc22 = A20*W20 + A21*W21 + A22*W22;
    float j00 = fx / zs,  j02 = -fx * x_c / (zs * zs);
    float j11 = fy / zs,  j12 = -fy * y_c / (zs * zs);
    float c00 = j00*j00*Sc00 + 2.f*j00*j02*Sc02 + j02*j02*Sc22;
    float c01 = j00*(Sc01*j11 + Sc02*j12) + j02*(Sc12*j11 + Sc22*j12);
    float c11 = j11*j11*Sc11 + 2.f*j11*j12*Sc12 + j12*j12*Sc22;
    float a  = fmaxf(c00, 0.3f);
    float cc = fmaxf(c11, 0.3f);
    float bb = c01;
    float det = a * cc - bb * bb;
    bool valid = (z > 0.01f) && (det > 1e-8f);
    float det_s = (det > 1e-8f) ? det : 1.0f;
    float ia = cc / det_s, ib = -bb / det_s, ic = a / det_s;
    uu[gid] = u;  vv[gid] = v;
    cia[gid] = ia;  cib[gid] = ib;  cic[gid] = ic;
    cex[gid] = sqrtf(34.0f * a);    // ellipse {d2<=34} AABB half-extents
    cey[gid] = sqrtf(34.0f * cc);
    crbc[gid] = -bb / a;            // edge-min ratios (div-free cull)
    crba[gid] = -bb / cc;
    bool visible = valid && (z > 0.1f) &&
                   (u >= 0.f) && (u < (float)W) && (v >= 0.f) && (v < (float)H);
    ikey[gid] = visible ? __float_as_int(z) : INVIS_KEY;
}

// -- K2: rank one 64-i chunk per block; j-loop split across 4 waves --
__global__ __launch_bounds__(RPW * 64) void rankpack_kernel(
    const int* __restrict__ ikey,
    const float* __restrict__ uu, const float* __restrict__ vv,
    const float* __restrict__ cia, const float* __restrict__ cib,
    const float* __restrict__ cic, const float* __restrict__ cex,
    const float* __restrict__ cey, const float* __restrict__ crbc,
    const float* __restrict__ crba,
    const float* __restrict__ opac, const float* __restrict__ sem,
    float4* __restrict__ pk0, float4* __restrict__ pk1,
    float4* __restrict__ pk2,
    float* __restrict__ psem, int* __restrict__ pcount,
    int B, int M, int N, int C)
{
    __shared__ int rsum[RPW][64];
    __shared__ int tsum[RPW];
    int wave  = threadIdx.x >> 6;
    int lane  = threadIdx.x & 63;
    int nch64 = (N + 63) >> 6;
    int chunk = blockIdx.x;
    int bm = chunk / nch64;
    int cl = chunk - bm * nch64;
    int i  = (cl << 6) + lane;
    const int* kb = ikey + (size_t)bm * N;
    int ki  = (i < N) ? kb[i] : INVIS_KEY;
    int kip = ki + 1;                 // tie-break: j<i counts kj<=ki
    int rank = 0, tot = 0;
    for (int jc = wave; jc < nch64; jc += RPW) {
        int jn = (jc << 6) + lane;
        int kj = (jn < N) ? kb[jn] : INVIS_KEY;
        tot += (int)__popcll(__ballot(kj != INVIS_KEY));
        if (jc < cl) {
#pragma unroll
            for (int gg = 0; gg < 64; ++gg)
                rank += (__builtin_amdgcn_readlane(kj, gg) < kip);
        } else if (jc > cl) {
#pragma unroll
            for (int gg = 0; gg < 64; ++gg)
                rank += (__builtin_amdgcn_readlane(kj, gg) < ki);
        } else {            // straddle chunk: j < i  <=>  gg < lane
#pragma unroll
            for (int gg = 0; gg < 64; ++gg) {
                int kk = (gg < lane) ? kip : ki;
                rank += (__builtin_amdgcn_readlane(kj, gg) < kk);
            }
        }
    }
    rsum[wave][lane] = rank;
    if (lane == 0) tsum[wave] = tot;
    __syncthreads();
    if (wave != 0) return;
    rank = rsum[0][lane] + rsum[1][lane] + rsum[2][lane] + rsum[3][lane];
    tot  = tsum[0] + tsum[1] + tsum[2] + tsum[3];
    if (cl == 0 && lane == 0) pcount[bm] = tot;
    if (i < N && ki != INVIS_KEY) {
        int b = bm / M;
        size_t src = (size_t)bm * N + i;
        size_t dst = (size_t)bm * N + rank;
        float z = __int_as_float(ki);
        pk0[dst] = make_float4(uu[src], vv[src], cex[src], cey[src]);
        pk1[dst] = make_float4(cia[src], cib[src], cic[src],
                               opac[(size_t)b * N + i]);
        pk2[dst] = make_float4(fminf(fmaxf(z, 0.1f), 100.0f),
                               crbc[src], crba[src], 0.f);
        const float* spc = sem + ((size_t)b * N + i) * C;
        float* dpc = psem + dst * C;
        int c4 = C & ~3;
        for (int q = 0; q < c4; q += 4)
            *(float4*)(dpc + q) = *(const float4*)(spc + q);
        for (int q = c4; q < C; ++q) dpc[q] = spc[q];
    }
}

// ---- K3: one tile per block; fused bin (scan->LDS list) + raster ----
__global__ __launch_bounds__(RTPB) void raster_kernel(
    const float4* __restrict__ pk0, const float4* __restrict__ pk1,
    const float4* __restrict__ pk2,
    const float* __restrict__ psem, const int* __restrict__ pcount,
    float* __restrict__ out,
    int BM, int N, int C, int H, int W, int ntx, int nty)
{
    // 40 KB buffer: bin phase uses it as ints (stage 2048 + flat 2048 + wcnt 16
    // = 16.4 KB); combine phase reuses it as comb[NSEG*ROWS2*64] floats.
    // Lifetimes separated by __syncthreads().
    __shared__ float sh[NSEG * ROWS2 * 64];
    int* stage = (int*)sh;                    // [NSEG][SEGCAP]
    int* flat  = stage + NSEG * SEGCAP;       // [<=2048], depth-ordered list
    int* wcnt  = flat + NSEG * SEGCAP;        // [NSEG]
    float* comb = sh;

    int wave = threadIdx.x >> 6;
    int lane = threadIdx.x & 63;
    int tile = blockIdx.x;
    int tpv = ntx * nty;
    int bm  = tile / tpv;
    int rem = tile - bm * tpv;
    int tyi = rem / ntx;
    int txi = rem - tyi * ntx;
    int lx = lane & 7, ly = lane >> 3;
    float fxp = (float)(txi * 8 + lx), fyp = (float)(tyi * 8 + ly);
    float x0 = (float)(txi * 8),     y0 = (float)(tyi * 8);
    float x1 = (float)(txi * 8 + 7), y1 = (float)(tyi * 8 + 7);

    // ---- phase 1: scan + cull into ordered LDS staging ----
    int cnt = pcount[bm];
    int seg = (cnt + NSEG - 1) / NSEG;
    int gs = wave * seg;
    int ge = min(gs + seg, cnt);
    int nlocal = 0;
    for (int base = gs; base < ge; base += 64) {
        int g = base + lane;
        bool inr = g < ge;
        int gc = inr ? g : (ge - 1);
        size_t src = (size_t)bm * N + gc;
        float4 P0 = pk0[src];
        float4 P1 = pk1[src];
        float4 P2 = pk2[src];
        float dx0 = x0 - P0.x, dx1 = x1 - P0.x;
        float dy0 = y0 - P0.y, dy1 = y1 - P0.y;
        bool aabb = (dx0 <= P0.z) && (-dx1 <= P0.z) &&
                    (dy0 <= P0.w) && (-dy1 <= P0.w);
        bool inside = (dx0 <= 0.f) && (dx1 >= 0.f) && (dy0 <= 0.f) && (dy1 >= 0.f);
        float t, q0, q1, q2, q3;
        t  = fminf(fmaxf(P2.y * dx0, dy0), dy1);
        q0 = P1.x * dx0 * dx0 + t * (P1.z * t + 2.f * P1.y * dx0);
        t  = fminf(fmaxf(P2.y * dx1, dy0), dy1);
        q1 = P1.x * dx1 * dx1 + t * (P1.z * t + 2.f * P1.y * dx1);
        t  = fminf(fmaxf(P2.z * dy0, dx0), dx1);
        q2 = P1.z * dy0 * dy0 + t * (P1.x * t + 2.f * P1.y * dy0);
        t  = fminf(fmaxf(P2.z * dy1, dx0), dx1);
        q3 = P1.z * dy1 * dy1 + t * (P1.x * t + 2.f * P1.y * dy1);
        float mind2 = inside ? 0.f : fminf(fminf(q0, q1), fminf(q2, q3));
        unsigned long long mask = __ballot(inr && aabb && (mind2 <= 34.0f));
        if ((mask >> lane) & 1ull) {
            int pos = nlocal + (int)__popcll(mask & ((1ull << lane) - 1ull));
            stage[wave * SEGCAP + pos] = g;
        }
        nlocal += (int)__popcll(mask);
    }
    if (lane == 0) wcnt[wave] = nlocal;
    __syncthreads();
    int offs = 0, total = 0;
    for (int w = 0; w < NSEG; ++w) {
        int c = wcnt[w];
        if (w < wave) offs += c;
        total += c;
    }
    for (int i2 = lane; i2 < nlocal; i2 += 64)
        flat[offs + i2] = stage[wave * SEGCAP + i2];
    __syncthreads();

    // ---- phase 2: process equal slices of the LDS survivor list ----
    int seg2 = (total + NSEG - 1) / NSEG;
    gs = wave * seg2;
    ge = min(gs + seg2, total);

    float T = 1.0f, accA = 0.f, accD = 0.f;
    float accS[MAXC];
#pragma unroll
    for (int q = 0; q < MAXC; ++q) accS[q] = 0.f;

    for (int base = gs; base < ge; base += 64) {
        int g = base + lane;
        bool inr = g < ge;
        int idx = flat[inr ? g : (ge - 1)];
        size_t src = (size_t)bm * N + idx;
        float4 P0 = pk0[src];        // u, v, -, -
        float4 P1 = pk1[src];        // ia, ib, ic, op
        float4 P2 = pk2[src];        // dz, -, -, -
        float sf[MAXC];
        {
            const float4* spc = (const float4*)(psem + src * MAXC);
#pragma unroll
            for (int q = 0; q < MAXC / 4; ++q) {
                float4 f = spc[q];
                sf[q*4+0] = f.x; sf[q*4+1] = f.y; sf[q*4+2] = f.z; sf[q*4+3] = f.w;
            }
        }
        int nev = min(64, ge - base);
        for (int gg = 0; gg < nev; ++gg) {   // list order = depth order
            float u  = rlf(P0.x, gg), v  = rlf(P0.y, gg);
            float ia = rlf(P1.x, gg), ib = rlf(P1.y, gg), ic = rlf(P1.z, gg);
            float dx = fxp - u, dy = fyp - v;
            float d2 = ia*dx*dx + ic*dy*dy + 2.0f*ib*(dx*dy);
            float gvl = __expf(-0.5f * d2);
            float alpha = fminf(rlf(P1.w, gg) * gvl, 0.99f);
            float w = T * alpha;
            T -= w;
            accD += w * rlf(P2.x, gg);
            accA += w;
#pragma unroll
            for (int ch = 0; ch < MAXC; ++ch) accS[ch] += w * rlf(sf[ch], gg);
        }
    }
    __syncthreads();   // end of bin-buffer lifetime; comb reuse begins

    // ---- phase 3: two-pass segment combine ----
    int px = lane;
    int pxx = txi * 8 + (px & 7);
    int pyy = tyi * 8 + (px >> 3);
    bool inb = (pxx < W) && (pyy < H);
    size_t HW  = (size_t)H * W;
    size_t pix = (size_t)pyy * W + pxx;
    size_t BMHW = (size_t)BM * HW;

    // pass 1 rows: 0=T, 1=D, 2=A, 3..8=S0..S5
    float* my = comb + (wave * ROWS1) * 64 + lane;
    my[0 * 64] = T;
    my[1 * 64] = accD;
    my[2 * 64] = accA;
#pragma unroll
    for (int k = 0; k < 6; ++k) my[(3 + k) * 64] = accS[k];
    __syncthreads();

    float pre[NSEG];
    pre[0] = 1.f;
#pragma unroll
    for (int w = 1; w < NSEG; ++w)
        pre[w] = pre[w-1] * comb[((w-1) * ROWS1) * 64 + px];

    if (wave < 8) {   // pass 1 outputs: depth, sem0..5, alpha
        int row, outc;
        if (wave == 0)      { row = 1;        outc = 0; }       // depth
        else if (wave <= 6) { row = 2 + wave; outc = wave; }    // sem wave-1
        else                { row = 2;        outc = C + 1; }   // alpha
        float val = 0.f;
#pragma unroll
        for (int w = 0; w < NSEG; ++w)
            val += pre[w] * comb[(w * ROWS1 + row) * 64 + px];
        if (inb) {
            float* dst;
            if (outc == 0)      dst = out + (size_t)bm * HW + pix;
            else if (outc <= C) dst = out + BMHW + (size_t)bm * C * HW + (size_t)(outc-1) * HW + pix;
            else                dst = out + BMHW + BMHW * C + (size_t)bm * HW + pix;
            *dst = val;
        }
    }
    __syncthreads();   // pass-1 reads done before overwrite

    // pass 2 rows: 0..9 = S6..S15
    float* my2 = comb + (wave * ROWS2) * 64 + lane;
#pragma unroll
    for (int k = 0; k < 10; ++k) my2[k * 64] = accS[6 + k];
    __syncthreads();

    if (wave < 10) {   // sem6..15
        int k = wave;
        float val = 0.f;
#pragma unroll
        for (int w = 0; w < NSEG; ++w)
            val += pre[w] * comb[(w * ROWS2 + k) * 64 + px];
        if (inb) {
            int outc = 7 + k;   // sem index 6+k
            float* dst = out + BMHW + (size_t)bm * C * HW + (size_t)(outc-1) * HW + pix;
            *dst = val;
        }
    }
}

extern "C" void kernel_launch(void* const* d_in, const int* in_sizes, int n_in,
                              void* d_out, int out_size, void* d_ws, size_t ws_size,
                              hipStream_t stream) {
    const float* means  = (const float*)d_in[0];
    const float* scales = (const float*)d_in[1];
    const float* rots   = (const float*)d_in[2];
    const float* opac   = (const float*)d_in[3];
    const float* sem    = (const float*)d_in[4];
    const float* intr   = (const float*)d_in[5];
    const float* c2e    = (const float*)d_in[6];
    float* out = (float*)d_out;

    int B  = 1;
    int BM = in_sizes[6] / 16;         // cam2ego is (B,M,4,4)
    int M  = BM / B;
    int N  = in_sizes[0] / (3 * B);    // means (B,N,3)
    int C  = in_sizes[4] / (B * N);    // semantic_features (B,N,C)
    long HWl = (long)out_size / ((long)BM * (C + 2));
    int H = (int)(sqrt((double)HWl) + 0.5);
    int W = (int)(HWl / H);
    int ntx = (W + 7) / 8, nty = (H + 7) / 8;
    int ntiles = ntx * nty * BM;
    int nch64  = (N + 63) >> 6;

    float* ws = (float*)d_ws;
    size_t off = 0;
    size_t BMN  = (size_t)BM * N;
    int*   ikey = (int*)(ws + off); off += BMN;
    float* uu   = ws + off; off += BMN;
    float* vv   = ws + off; off += BMN;
    float* cia  = ws + off; off += BMN;
    float* cib  = ws + off; off += BMN;
    float* cic  = ws + off; off += BMN;
    float* cex  = ws + off; off += BMN;
    float* cey  = ws + off; off += BMN;
    float* crbc = ws + off; off += BMN;
    float* crba = ws + off; off += BMN;
    off = (off + 3) & ~(size_t)3;            // float4 alignment
    float4* pk0 = (float4*)(ws + off); off += BMN * 4;
    float4* pk1 = (float4*)(ws + off); off += BMN * 4;
    float4* pk2 = (float4*)(ws + off); off += BMN * 4;
    float* psem = ws + off; off += BMN * C;
    int* pcount = (int*)(ws + off); off += BM;

    int tot = BM * N;
    preprocess_kernel<<<(tot + 255) / 256, 256, 0, stream>>>(
        means, scales, rots, intr, c2e,
        ikey, uu, vv, cia, cib, cic, cex, cey, crbc, crba, B, M, N, W, H);

    rankpack_kernel<<<BM * nch64, RPW * 64, 0, stream>>>(
        ikey, uu, vv, cia, cib, cic, cex, cey, crbc, crba, opac, sem,
        pk0, pk1, pk2, psem, pcount, B, M, N, C);

    raster_kernel<<<ntiles, RTPB, 0, stream>>>(
        pk0, pk1, pk2, psem, pcount, out, BM, N, C, H, W, ntx, nty);
}